// Round 7
// baseline (177.110 us; speedup 1.0000x reference)
//
#include <hip/hip_runtime.h>
#include <hip/hip_bf16.h>
#include <math.h>

#define BB 8
#define CC 128
#define DD 64
#define TT 64
#define PP 4096
#define H1 66
#define LW 20
#define MARGINF 0.1f
#define NEG_SENTINEL -1.0e30f

// workspace layout (float offsets)
#define Y0_OFF   0            // y0w bf16 channel-last [8][66][66][128] = 2230272 f
#define VT_OFF   2230272      // vT bf16 [8][64][64][128] = 2097152 f
#define BP0_OFF  4327424      // Bpack(Wc0) 16x16 layout = 73728 f
#define NL_OFF   4401152      // per-sentence neg-loss [8] (old BP1 slot, unused gap)
#define W0_OFF   4479236      // weight0 [66][66] = 4356
#define W1_OFF   4483592      // weight1 [64][64] = 4096
#define G0_OFF   4487688      // [8][128]
#define G1_OFF   4488712      // [8][128]
#define S_OFF    4489736      // si [8][4096] = 32768 (diag maps only)
#define SCP_OFF  4522504      // packed scores u64 [64] = 128 f
#define BP1S_OFF 4522632      // 8x gate-scaled Bpack(Wc1*g0[i]) = 8*73728 f = 589824 f
// total ≈ 5112456 floats ≈ 20.5 MB

typedef __attribute__((ext_vector_type(8))) short bf16x8;
typedef __attribute__((ext_vector_type(4))) float f32x4;

// LDS (row,col) stride in shorts: 44 (=88B), conflict-light b128 access
#define ASTR 44

__device__ __forceinline__ unsigned f2bf(float f) {
  union { float f; unsigned u; } v; v.f = f;
  unsigned r = v.u + 0x7fffu + ((v.u >> 16) & 1u);   // RNE (setup only)
  return r >> 16;
}
__device__ __forceinline__ float bf2f(unsigned hw) {
  union { unsigned u; float f; } v; v.u = hw << 16;
  return v.f;
}
// native cast: compiler emits v_cvt_pk for pairs (m240)
__device__ __forceinline__ unsigned cvt_bf(float x) {
  __hip_bfloat16 h = __float2bfloat16(x);
  union { __hip_bfloat16 h; unsigned short u; } cv; cv.h = h;
  return (unsigned)cv.u;
}

// sign-select on 2 packed bf16: keep half iff sign(v) == wanted sign bit in W.
// relu(g*v)*Wc1 == select(v) * (Wc1*g), select(v) = g>0 ? max(v,0) : min(v,0)
__device__ __forceinline__ unsigned selbf(unsigned d, unsigned W) {
  unsigned diff = (d ^ W) & 0x80008000u;     // sign mismatch bits
  unsigned full = (diff >> 15) * 0xFFFFu;    // expand to half-word masks
  return d & ~full;                          // zero mismatched halves
}

// async 16B global->LDS DMA (dest = wave-uniform base; HW adds lane*16)
__device__ __forceinline__ void dma16(const void* g, void* l) {
  __builtin_amdgcn_global_load_lds(
      (__attribute__((address_space(1))) void*)g,
      (__attribute__((address_space(3))) void*)l, 16, 0, 0);
}

// ---------------- gates: pooled words -> g0,g1 (must precede setup: B1 pack needs g0)
__global__ __launch_bounds__(256) void gates_kernel(
    const float* __restrict__ words, const float* __restrict__ w_masks,
    const float* __restrict__ Wp0, const float* __restrict__ bp0,
    const float* __restrict__ Wp1, const float* __restrict__ bp1,
    float* __restrict__ ws)
{
  __shared__ float smem[CC];
  int i = blockIdx.x;
  int t = threadIdx.x;
  if (t < CC) {
    float wsum = 0.f, acc = 0.f;
    for (int l = 0; l < LW; ++l) {
      float wm = w_masks[i * LW + l];
      wsum += wm;
      acc += words[(i * LW + l) * CC + t] * wm;
    }
    smem[t] = acc / fmaxf(wsum, 1.f);
  }
  __syncthreads();
  {
    int c = t & 127;
    const float* Wp = (t < 128) ? Wp0 : Wp1;
    const float* bp = (t < 128) ? bp0 : bp1;
    float a = bp[c];
    for (int k = 0; k < CC; ++k) a += smem[k] * Wp[k * CC + c];
    float g = tanhf(a);
    float* gout = ws + ((t < 128) ? G0_OFF : G1_OFF);
    gout[i * CC + c] = g;
  }
}

// ---------------- fused setup: pack B0, pack B1 x8 (one-read-eight-writes),
// transpose, w0/w1, scp zero
__global__ __launch_bounds__(256) void setup_kernel(
    const float* __restrict__ vmap, const float* __restrict__ v_mask,
    const float* __restrict__ Wc0, const float* __restrict__ Wc1,
    float* __restrict__ ws)
{
  __shared__ float smem[64 * 129];
  int bid = blockIdx.x;
  int t = threadIdx.x;

  if (bid < 576) {
    // B0 pack (unscaled)
    unsigned short* dst = (unsigned short*)(ws + BP0_OFF);
    int idx = bid * 256 + t;
    int j    = idx & 7;
    int lane = (idx >> 3) & 63;
    int cog  = (idx >> 9) & 7;
    int cic  = (idx >> 12) & 3;
    int kk   = idx >> 14;
    int co = cog * 16 + (lane & 15);
    int ci = cic * 32 + (lane >> 4) * 8 + j;
    dst[idx] = (unsigned short)f2bf(Wc0[(co * CC + ci) * 9 + kk]);
  } else if (bid < 1152) {
    // B1S pack: read each Wc1 element ONCE, write 8 gate-scaled copies
    for (int v = t; v < 8 * CC; v += 256) smem[v] = ws[G0_OFF + v];
    __syncthreads();
    int idx = (bid - 576) * 256 + t;
    int j    = idx & 7;
    int lane = (idx >> 3) & 63;
    int cog  = (idx >> 9) & 7;
    int cic  = (idx >> 12) & 3;
    int kk   = idx >> 14;
    int co = cog * 16 + (lane & 15);
    int ci = cic * 32 + (lane >> 4) * 8 + j;
    float wv = Wc1[(co * CC + ci) * 9 + kk];
    unsigned short* dst = (unsigned short*)(ws + BP1S_OFF);
#pragma unroll
    for (int si = 0; si < 8; ++si)
      dst[si * 147456 + idx] = (unsigned short)f2bf(wv * smem[si * CC + ci]);
  } else if (bid < 1664) {
    unsigned short* vT = (unsigned short*)(ws + VT_OFF);
    int b = bid - 1152;
    int y = b & 63, n = b >> 6;
    int x = t & 63, c4 = t >> 6;
    for (int rep = 0; rep < 32; ++rep) {
      int ci = rep * 4 + c4;
      smem[x * 129 + ci] = vmap[(((size_t)n * CC + ci) * DD + y) * TT + x];
    }
    __syncthreads();
    for (int rep = 0; rep < 16; ++rep) {
      int v = t + rep * 256;
      int xx = v >> 6, cip = v & 63;
      float a = smem[xx * 129 + cip * 2];
      float b2 = smem[xx * 129 + cip * 2 + 1];
      unsigned pk = f2bf(a) | (f2bf(b2) << 16);
      *(unsigned*)&vT[(((size_t)(n * DD + y) * TT + xx)) * CC + cip * 2] = pk;
    }
  } else {
    if (t < 128) ((unsigned*)(ws + SCP_OFF))[t] = 0u;   // zero packed scores
    float* w0 = ws + W0_OFF;
    float* w1 = ws + W1_OFF;
    for (int idx = t; idx < H1 * H1; idx += 256) {
      int y = idx / H1, x = idx % H1;
      float cnt = 0.f;
      for (int ky = 0; ky < 3; ++ky)
        for (int kx = 0; kx < 3; ++kx) {
          int iy = y + ky - 2, ix = x + kx - 2;
          if (iy >= 0 && iy < DD && ix >= 0 && ix < TT) cnt += v_mask[iy * TT + ix];
        }
      w0[idx] = (cnt > 0.f) ? 1.f / fmaxf(cnt, 1.f) : 0.f;
    }
    __syncthreads();
    for (int idx = t; idx < DD * TT; idx += 256) {
      int y = idx / TT, x = idx % TT;
      float cnt = 0.f;
      for (int ky = 0; ky < 3; ++ky)
        for (int kx = 0; kx < 3; ++kx)
          cnt += (w0[(y + ky) * H1 + (x + kx)] > 0.f) ? 1.f : 0.f;
      w1[idx] = (cnt > 0.f) ? 1.f / fmaxf(cnt, 1.f) : 0.f;
    }
  }
}

// conv1: 1 output row per block (grid 66 x 8, 2 blocks/CU); 16x16x32 MFMA  (unchanged)
__global__ __launch_bounds__(256, 2) void conv1_mfma(
    const float* __restrict__ bc0, float* __restrict__ ws)
{
  const unsigned short* vT = (const unsigned short*)(ws + VT_OFF);
  const unsigned short* Bp = (const unsigned short*)(ws + BP0_OFF);
  const float* w0arr = ws + W0_OFF;
  unsigned short* y0w = (unsigned short*)(ws + Y0_OFF);

  __shared__ unsigned short Alds[3 * 68 * ASTR];   // 17952 B

  int t = threadIdx.x;
  int r0 = blockIdx.x;                 // output row 0..65
  int n = blockIdx.y;
  int lane = t & 63, w = t >> 6;       // w = co quarter
  int l15 = lane & 15, l4 = lane >> 4;
  int co0 = w * 32;

  f32x4 acc[5][2];
#pragma unroll
  for (int mf = 0; mf < 5; ++mf)
#pragma unroll
    for (int nf = 0; nf < 2; ++nf) acc[mf][nf] = (f32x4){0.f, 0.f, 0.f, 0.f};

  for (int cic = 0; cic < 4; ++cic) {
    __syncthreads();
    for (int u = t; u < 816; u += 256) {
      int cig = u & 3, rest = u >> 2;
      int col = rest % 68, r = rest / 68;
      int iy = r0 - 2 + r, ix = col - 2;
      uint4 val = {0u, 0u, 0u, 0u};
      if (iy >= 0 && iy < DD && ix >= 0 && ix < TT)
        val = *(const uint4*)&vT[(((size_t)(n * DD + iy) * TT + ix)) * CC + cic * 32 + cig * 8];
      *(uint4*)&Alds[(r * 68 + col) * ASTR + cig * 8] = val;
    }
    __syncthreads();
    __builtin_amdgcn_s_setprio(1);
#pragma unroll
    for (int kk = 0; kk < 9; ++kk) {
      int ky = kk / 3, kx = kk % 3;
      bf16x8 af[5], bfr[2];
#pragma unroll
      for (int mf = 0; mf < 5; ++mf) {
        int c = mf * 16 + l15;
        int cc = c > 65 ? 65 : c;
        af[mf] = *(const bf16x8*)&Alds[(ky * 68 + cc + kx) * ASTR + l4 * 8];
      }
#pragma unroll
      for (int nf = 0; nf < 2; ++nf)
        bfr[nf] = *(const bf16x8*)&Bp[(((kk * 4 + cic) * 8 + w * 2 + nf) * 64 + lane) * 8];
#pragma unroll
      for (int mf = 0; mf < 5; ++mf)
#pragma unroll
        for (int nf = 0; nf < 2; ++nf)
          acc[mf][nf] = __builtin_amdgcn_mfma_f32_16x16x32_bf16(af[mf], bfr[nf], acc[mf][nf], 0, 0, 0);
    }
    __builtin_amdgcn_s_setprio(0);
  }

  int y = r0;
#pragma unroll
  for (int nf = 0; nf < 2; ++nf) {
    int co = co0 + nf * 16 + l15;
    float bcv = bc0[co];
#pragma unroll
    for (int mf = 0; mf < 5; ++mf)
#pragma unroll
      for (int rg = 0; rg < 4; ++rg) {
        int c = mf * 16 + l4 * 4 + rg;
        if (c < H1) {
          float v = (acc[mf][nf][rg] + bcv) * w0arr[y * H1 + c];
          y0w[((size_t)(n * H1 + y) * H1 + c) * CC + co] = (unsigned short)cvt_bf(v);
        }
      }
  }
}

// conv2 R23: proven R20 structure + B-fragments staged to LDS via DMA.
// The MFMA loop previously re-read Bp from global every kk (36 deep-latency
// loads/wave/cic, unhoistable) => MfmaUtil 33%. Now: after loop-top
// __syncthreads (prior Blds reads done), issue 72 fire-and-forget
// global_load_lds (18/wave, ZERO live VGPRs) covering this cic's 72KB B-slice;
// they fly under the staging phase and drain at the pre-MFMA barrier.
// MFMA cluster identical except bfr reads Blds (ds_read_b128) not global.
// LDS ~111KB -> 1 block/CU (deliberate: per-kk latency 300-700cy -> ~150cy).
__global__ __launch_bounds__(256, 2) void conv2_mfma(
    const float* __restrict__ bc1, const float* __restrict__ W2d,
    const float* __restrict__ b2d, const float* __restrict__ v_mask,
    const int* __restrict__ valid_num, float* __restrict__ ws,
    float* __restrict__ out)
{
  const unsigned short* y0w = (const unsigned short*)(ws + Y0_OFF);
  const float* w1m = ws + W1_OFF;
  const float* g0 = ws + G0_OFF;
  const float* g1 = ws + G1_OFF;
  unsigned long long* scp = (unsigned long long*)(ws + SCP_OFF);

  __shared__ unsigned short Alds[6 * 66 * ASTR];   // 34848 B
  __shared__ unsigned short Blds[72 * 512];        // 73728 B: [kk*8+s][64 lanes][8]
  __shared__ unsigned msk[16][4];                  // sign masks per (cic,cig)
  __shared__ float redl[2][4][64];
  __shared__ unsigned long long kred[4];

  int t = threadIdx.x;
  int r0 = blockIdx.x;                        // output rows r0*4 .. +3 (r0 in 0..15)
  int i = blockIdx.y & 7, n = blockIdx.y >> 3;   // n-major: L2 locality on y0w[n]
  int lane = t & 63, w = t >> 6;
  int wr = w >> 1, wc = w & 1;
  int l15 = lane & 15, l4 = lane >> 4;

  const unsigned short* Bp = (const unsigned short*)(ws + BP1S_OFF) + (size_t)i * 147456;

  if (t < 16) {                               // t = cic*4+cig -> channels t*8..t*8+7
    int ch = t * 8;
    msk[t][0] = (g0[i * CC + ch + 0] > 0.f ? 0u : 0x8000u) | (g0[i * CC + ch + 1] > 0.f ? 0u : 0x80000000u);
    msk[t][1] = (g0[i * CC + ch + 2] > 0.f ? 0u : 0x8000u) | (g0[i * CC + ch + 3] > 0.f ? 0u : 0x80000000u);
    msk[t][2] = (g0[i * CC + ch + 4] > 0.f ? 0u : 0x8000u) | (g0[i * CC + ch + 5] > 0.f ? 0u : 0x80000000u);
    msk[t][3] = (g0[i * CC + ch + 6] > 0.f ? 0u : 0x8000u) | (g0[i * CC + ch + 7] > 0.f ? 0u : 0x80000000u);
  }

  f32x4 acc[8][4];
#pragma unroll
  for (int mf = 0; mf < 8; ++mf)
#pragma unroll
    for (int nf = 0; nf < 4; ++nf) acc[mf][nf] = (f32x4){0.f, 0.f, 0.f, 0.f};

  for (int cic = 0; cic < 4; ++cic) {
    __syncthreads();   // prior MFMA's Blds/Alds reads complete (lgkm drained)

    // B-slice DMA for THIS cic: 72 x 1KB slices, wave w takes q = w*18..+17.
    // dest is wave-uniform (HW adds lane*16); src per-lane. Zero live VGPRs.
    for (int j = 0; j < 18; ++j) {
      int q = w * 18 + j;
      int kkq = q >> 3, sq = q & 7;
      dma16((const char*)Bp + ((((kkq << 2) + cic) * 8 + sq) * 64 + lane) * 16,
            &Blds[q * 512]);
    }

    // stage 6 rows x 66 cols x 32ci: 1584 uint4s; select applied via sign bits
    {
      uint4 mv = *(const uint4*)&msk[(cic << 2) | (t & 3)][0];
      for (int u = t; u < 1584; u += 256) {
        int cig = u & 3, cr = u >> 2;
        int col = cr % 66, row = cr / 66;       // row 0..5
        const unsigned short* src = y0w
            + ((size_t)((n * H1 + r0 * 4 + row) * H1 + col)) * CC + cic * 32 + cig * 8;
        uint4 raw = *(const uint4*)src;
        uint4 pk;
        pk.x = selbf(raw.x, mv.x);
        pk.y = selbf(raw.y, mv.y);
        pk.z = selbf(raw.z, mv.z);
        pk.w = selbf(raw.w, mv.w);
        *(uint4*)&Alds[(row * 66 + col) * ASTR + cig * 8] = pk;
      }
    }
    __syncthreads();   // full vmcnt drain: staging loads AND B-DMAs landed
    __builtin_amdgcn_s_setprio(1);
#pragma unroll
    for (int kk = 0; kk < 9; ++kk) {
      int ky = kk / 3, kx = kk % 3;
      bf16x8 af[8], bfr[4];
#pragma unroll
      for (int mf = 0; mf < 8; ++mf) {
        int row = wr * 2 + (mf >> 2) + ky;          // 0..5
        int col = (mf & 3) * 16 + l15 + kx;         // 0..65
        af[mf] = *(const bf16x8*)&Alds[(row * 66 + col) * ASTR + l4 * 8];
      }
#pragma unroll
      for (int nf = 0; nf < 4; ++nf)
        bfr[nf] = *(const bf16x8*)&Blds[((kk * 8 + wc * 4 + nf) * 64 + lane) * 8];
#pragma unroll
      for (int mf = 0; mf < 8; ++mf)
#pragma unroll
        for (int nf = 0; nf < 4; ++nf)
          acc[mf][nf] = __builtin_amdgcn_mfma_f32_16x16x32_bf16(af[mf], bfr[nf], acc[mf][nf], 0, 0, 0);
    }
    __builtin_amdgcn_s_setprio(0);
  }

  // epilogue: relu((acc+bc1)*g1)*W2d, reduce over co; weight1 factored out (w1>=0)
  float part[8][4];
#pragma unroll
  for (int mf = 0; mf < 8; ++mf)
#pragma unroll
    for (int rg = 0; rg < 4; ++rg) part[mf][rg] = 0.f;
#pragma unroll
  for (int nf = 0; nf < 4; ++nf) {
    int co = wc * 64 + nf * 16 + l15;
    float bcv = bc1[co];
    float gv = g1[i * CC + co];
    float wv = W2d[co];
#pragma unroll
    for (int mf = 0; mf < 8; ++mf)
#pragma unroll
      for (int rg = 0; rg < 4; ++rg) {
        float z = (acc[mf][nf][rg] + bcv) * gv;
        part[mf][rg] += fmaxf(z, 0.f) * wv;
      }
  }
#pragma unroll
  for (int mask = 1; mask < 16; mask <<= 1)
#pragma unroll
    for (int mf = 0; mf < 8; ++mf)
#pragma unroll
      for (int rg = 0; rg < 4; ++rg)
        part[mf][rg] += __shfl_xor(part[mf][rg], mask, 64);
  if (l15 == 0) {
#pragma unroll
    for (int mf = 0; mf < 8; ++mf)
#pragma unroll
      for (int rg = 0; rg < 4; ++rg)
        redl[wc][wr * 2 + (mf >> 2)][(mf & 3) * 16 + l4 * 4 + rg] = part[mf][rg];
  }
  __syncthreads();
  {
    int row = t >> 6, col = t & 63;
    int rowg = r0 * 4 + row;
    float v = redl[0][row][col] + redl[1][row][col];
    float logit = w1m[rowg * TT + col] * v + b2d[0];
    float sig = 1.f / (1.f + expf(-logit));
    bool m = (v_mask[rowg * TT + col] > 0.f) && (col < valid_num[n]);
    int p = rowg * TT + col;
    if (i == n) {
      ws[S_OFF + i * PP + p] = m ? sig : -INFINITY;           // for hard-neg mining
      out[1 + i * PP + p] = m ? sig : NEG_SENTINEL;           // positive_map output
    }
    unsigned long long key = 0ull;
    if (m) key = ((unsigned long long)__float_as_uint(sig) << 32)
                 | (unsigned long long)(0xFFFFFFFFu - (unsigned)p);
#pragma unroll
    for (int mk = 1; mk < 64; mk <<= 1) {
      unsigned lo = __shfl_xor((unsigned)key, mk, 64);
      unsigned hi = __shfl_xor((unsigned)(key >> 32), mk, 64);
      unsigned long long o = ((unsigned long long)hi << 32) | lo;
      if (o > key) key = o;
    }
    if (lane == 0) kred[w] = key;
  }
  __syncthreads();
  if (t == 0) {
    unsigned long long k = kred[0];
    if (kred[1] > k) k = kred[1];
    if (kred[2] > k) k = kred[2];
    if (kred[3] > k) k = kred[3];
    if (k) atomicMax(&scp[i * 8 + n], k);
  }
}

// hard-negative mining: one block per sentence (8 blocks x 256 thr)
__global__ __launch_bounds__(256) void mine_kernel(
    const float* __restrict__ iou_maps, const float* __restrict__ lam,
    float* __restrict__ ws)
{
  __shared__ float wred[4];
  int i = blockIdx.x;
  int t = threadIdx.x, lane = t & 63, w = t >> 6;
  const unsigned long long* scp = (const unsigned long long*)(ws + SCP_OFF);

  unsigned long long dk = scp[i * 9];                  // diag (i,i)
  float diag_sc = __uint_as_float((unsigned)(dk >> 32));
  int pidx = (int)(0xFFFFFFFFu - (unsigned)(dk & 0xFFFFFFFFu));
  float lamv = lam[0];
  const float* row = iou_maps + (size_t)pidx * PP;
  const float* si = ws + S_OFF + (size_t)i * PP;
  float hv = -INFINITY;
  for (int p = t; p < PP; p += 256) {
    float v = si[p];
    if (row[p] < lamv && isfinite(v)) hv = fmaxf(hv, v);
  }
#pragma unroll
  for (int m = 1; m < 64; m <<= 1) hv = fmaxf(hv, __shfl_xor(hv, m, 64));
  if (lane == 0) wred[w] = hv;
  __syncthreads();
  if (t == 0) {
    float h = fmaxf(fmaxf(wred[0], wred[1]), fmaxf(wred[2], wred[3]));
    ws[NL_OFF + i] = fmaxf(0.f, MARGINF + h - diag_sc);
  }
}

// final loss: 1 wave, sorting-network top-3 (unchanged math)
__global__ __launch_bounds__(64) void loss_kernel(
    float* __restrict__ ws, float* __restrict__ out)
{
  __shared__ float scsh[64];
  int lane = threadIdx.x;
  const unsigned long long* scp = (const unsigned long long*)(ws + SCP_OFF);
  scsh[lane] = __uint_as_float((unsigned)(scp[lane] >> 32));
  __syncthreads();

  float partial = 0.f;
  if (lane < 16) {
    int r = lane & 7;
    bool im = lane >= 8;
    float diag = scsh[r * 8 + r];
    float v[8];
#pragma unroll
    for (int j = 0; j < 8; ++j) {
      float scv = im ? scsh[j * 8 + r] : scsh[r * 8 + j];
      float h = fmaxf(0.f, MARGINF + scv - diag);
      v[j] = (j == r) ? 0.f : h;
    }
#define CE(a, b) { float mx = fmaxf(v[a], v[b]); float mn = fminf(v[a], v[b]); v[a] = mx; v[b] = mn; }
    CE(0,1) CE(2,3) CE(4,5) CE(6,7)
    CE(0,2) CE(1,3) CE(4,6) CE(5,7)
    CE(1,2) CE(5,6)
    CE(0,4) CE(1,5) CE(2,6) CE(3,7)
    CE(2,4) CE(3,5)
    CE(1,2) CE(3,4) CE(5,6)
#undef CE
    partial = v[0] + v[1] + v[2];
  } else if (lane >= 16 && lane < 24) {
    partial = ws[NL_OFF + lane - 16];
  }
#pragma unroll
  for (int m = 1; m < 64; m <<= 1) partial += __shfl_xor(partial, m, 64);
  if (lane == 0) out[0] = partial * 0.125f;
}

extern "C" void kernel_launch(void* const* d_in, const int* in_sizes, int n_in,
                              void* d_out, int out_size, void* d_ws, size_t ws_size,
                              hipStream_t stream)
{
  const float* v_map     = (const float*)d_in[0];
  const float* words     = (const float*)d_in[1];
  const float* w_masks   = (const float*)d_in[2];
  const float* v_mask    = (const float*)d_in[3];
  const int*   valid_num = (const int*)d_in[4];
  const float* iou_maps  = (const float*)d_in[5];
  const float* lam       = (const float*)d_in[6];
  const float* Wc0 = (const float*)d_in[7];
  const float* bc0 = (const float*)d_in[8];
  const float* Wc1 = (const float*)d_in[9];
  const float* bc1 = (const float*)d_in[10];
  const float* Wp0 = (const float*)d_in[11];
  const float* bp0 = (const float*)d_in[12];
  const float* Wp1 = (const float*)d_in[13];
  const float* bp1 = (const float*)d_in[14];
  const float* W2d = (const float*)d_in[15];
  const float* b2d = (const float*)d_in[16];
  float* ws  = (float*)d_ws;
  float* out = (float*)d_out;

  hipLaunchKernelGGL(gates_kernel, dim3(8), dim3(256), 0, stream,
                     words, w_masks, Wp0, bp0, Wp1, bp1, ws);
  hipLaunchKernelGGL(setup_kernel, dim3(1665), dim3(256), 0, stream,
                     v_map, v_mask, Wc0, Wc1, ws);
  hipLaunchKernelGGL(conv1_mfma, dim3(66, 8), dim3(256), 0, stream, bc0, ws);
  hipLaunchKernelGGL(conv2_mfma, dim3(16, 64), dim3(256), 0, stream,
                     bc1, W2d, b2d, v_mask, valid_num, ws, out);
  hipLaunchKernelGGL(mine_kernel, dim3(8), dim3(256), 0, stream, iou_maps, lam, ws);
  hipLaunchKernelGGL(loss_kernel, dim3(1), dim3(64), 0, stream, ws, out);
}

// Round 8
// 149.283 us; speedup vs baseline: 1.1864x; 1.1864x over previous
//
#include <hip/hip_runtime.h>
#include <hip/hip_bf16.h>
#include <math.h>

#define BB 8
#define CC 128
#define DD 64
#define TT 64
#define PP 4096
#define H1 66
#define LW 20
#define MARGINF 0.1f
#define NEG_SENTINEL -1.0e30f

// workspace layout (float offsets)
#define Y0_OFF   0            // y0w bf16 channel-last [8][66][66][128] = 2230272 f
#define VT_OFF   2230272      // vT bf16 [8][64][64][128] = 2097152 f
#define BP0_OFF  4327424      // Bpack(Wc0) 16x16 layout = 73728 f
#define NL_OFF   4401152      // per-sentence neg-loss [8] (old BP1 slot, unused gap)
#define W0_OFF   4479236      // weight0 [66][66] = 4356
#define W1_OFF   4483592      // weight1 [64][64] = 4096
#define G0_OFF   4487688      // [8][128]
#define G1_OFF   4488712      // [8][128]
#define S_OFF    4489736      // si [8][4096] = 32768 (diag maps only)
#define SCP_OFF  4522504      // packed scores u64 [64] = 128 f
#define BP1S_OFF 4522632      // 8x gate-scaled Bpack(Wc1*g0[i]) = 8*73728 f = 589824 f
// total ≈ 5112456 floats ≈ 20.5 MB

typedef __attribute__((ext_vector_type(8))) short bf16x8;
typedef __attribute__((ext_vector_type(4))) float f32x4;

// LDS (row,col) stride in shorts: 44 (=88B), conflict-light b128 access
#define ASTR 44

__device__ __forceinline__ unsigned f2bf(float f) {
  union { float f; unsigned u; } v; v.f = f;
  unsigned r = v.u + 0x7fffu + ((v.u >> 16) & 1u);   // RNE (setup only)
  return r >> 16;
}
__device__ __forceinline__ float bf2f(unsigned hw) {
  union { unsigned u; float f; } v; v.u = hw << 16;
  return v.f;
}
// native cast: compiler emits v_cvt_pk for pairs (m240)
__device__ __forceinline__ unsigned cvt_bf(float x) {
  __hip_bfloat16 h = __float2bfloat16(x);
  union { __hip_bfloat16 h; unsigned short u; } cv; cv.h = h;
  return (unsigned)cv.u;
}

// sign-select on 2 packed bf16: keep half iff sign(v) == wanted sign bit in W.
// relu(g*v)*Wc1 == select(v) * (Wc1*g), select(v) = g>0 ? max(v,0) : min(v,0)
__device__ __forceinline__ unsigned selbf(unsigned d, unsigned W) {
  unsigned diff = (d ^ W) & 0x80008000u;     // sign mismatch bits
  unsigned full = (diff >> 15) * 0xFFFFu;    // expand to half-word masks
  return d & ~full;                          // zero mismatched halves
}

// async 16B global->LDS DMA (dest = wave-uniform base; HW adds lane*16)
__device__ __forceinline__ void dma16(const void* g, void* l) {
  __builtin_amdgcn_global_load_lds(
      (__attribute__((address_space(1))) void*)g,
      (__attribute__((address_space(3))) void*)l, 16, 0, 0);
}

// ---------------- gates: pooled words -> g0,g1 (must precede setup: B1 pack needs g0)
__global__ __launch_bounds__(256) void gates_kernel(
    const float* __restrict__ words, const float* __restrict__ w_masks,
    const float* __restrict__ Wp0, const float* __restrict__ bp0,
    const float* __restrict__ Wp1, const float* __restrict__ bp1,
    float* __restrict__ ws)
{
  __shared__ float smem[CC];
  int i = blockIdx.x;
  int t = threadIdx.x;
  if (t < CC) {
    float wsum = 0.f, acc = 0.f;
    for (int l = 0; l < LW; ++l) {
      float wm = w_masks[i * LW + l];
      wsum += wm;
      acc += words[(i * LW + l) * CC + t] * wm;
    }
    smem[t] = acc / fmaxf(wsum, 1.f);
  }
  __syncthreads();
  {
    int c = t & 127;
    const float* Wp = (t < 128) ? Wp0 : Wp1;
    const float* bp = (t < 128) ? bp0 : bp1;
    float a = bp[c];
    for (int k = 0; k < CC; ++k) a += smem[k] * Wp[k * CC + c];
    float g = tanhf(a);
    float* gout = ws + ((t < 128) ? G0_OFF : G1_OFF);
    gout[i * CC + c] = g;
  }
}

// ---------------- fused setup: pack B0, pack B1 x8 (one-read-eight-writes),
// transpose, w0/w1, scp zero
__global__ __launch_bounds__(256) void setup_kernel(
    const float* __restrict__ vmap, const float* __restrict__ v_mask,
    const float* __restrict__ Wc0, const float* __restrict__ Wc1,
    float* __restrict__ ws)
{
  __shared__ float smem[64 * 129];
  int bid = blockIdx.x;
  int t = threadIdx.x;

  if (bid < 576) {
    // B0 pack (unscaled)
    unsigned short* dst = (unsigned short*)(ws + BP0_OFF);
    int idx = bid * 256 + t;
    int j    = idx & 7;
    int lane = (idx >> 3) & 63;
    int cog  = (idx >> 9) & 7;
    int cic  = (idx >> 12) & 3;
    int kk   = idx >> 14;
    int co = cog * 16 + (lane & 15);
    int ci = cic * 32 + (lane >> 4) * 8 + j;
    dst[idx] = (unsigned short)f2bf(Wc0[(co * CC + ci) * 9 + kk]);
  } else if (bid < 1152) {
    // B1S pack: read each Wc1 element ONCE, write 8 gate-scaled copies
    for (int v = t; v < 8 * CC; v += 256) smem[v] = ws[G0_OFF + v];
    __syncthreads();
    int idx = (bid - 576) * 256 + t;
    int j    = idx & 7;
    int lane = (idx >> 3) & 63;
    int cog  = (idx >> 9) & 7;
    int cic  = (idx >> 12) & 3;
    int kk   = idx >> 14;
    int co = cog * 16 + (lane & 15);
    int ci = cic * 32 + (lane >> 4) * 8 + j;
    float wv = Wc1[(co * CC + ci) * 9 + kk];
    unsigned short* dst = (unsigned short*)(ws + BP1S_OFF);
#pragma unroll
    for (int si = 0; si < 8; ++si)
      dst[si * 147456 + idx] = (unsigned short)f2bf(wv * smem[si * CC + ci]);
  } else if (bid < 1664) {
    unsigned short* vT = (unsigned short*)(ws + VT_OFF);
    int b = bid - 1152;
    int y = b & 63, n = b >> 6;
    int x = t & 63, c4 = t >> 6;
    for (int rep = 0; rep < 32; ++rep) {
      int ci = rep * 4 + c4;
      smem[x * 129 + ci] = vmap[(((size_t)n * CC + ci) * DD + y) * TT + x];
    }
    __syncthreads();
    for (int rep = 0; rep < 16; ++rep) {
      int v = t + rep * 256;
      int xx = v >> 6, cip = v & 63;
      float a = smem[xx * 129 + cip * 2];
      float b2 = smem[xx * 129 + cip * 2 + 1];
      unsigned pk = f2bf(a) | (f2bf(b2) << 16);
      *(unsigned*)&vT[(((size_t)(n * DD + y) * TT + xx)) * CC + cip * 2] = pk;
    }
  } else {
    if (t < 128) ((unsigned*)(ws + SCP_OFF))[t] = 0u;   // zero packed scores
    float* w0 = ws + W0_OFF;
    float* w1 = ws + W1_OFF;
    for (int idx = t; idx < H1 * H1; idx += 256) {
      int y = idx / H1, x = idx % H1;
      float cnt = 0.f;
      for (int ky = 0; ky < 3; ++ky)
        for (int kx = 0; kx < 3; ++kx) {
          int iy = y + ky - 2, ix = x + kx - 2;
          if (iy >= 0 && iy < DD && ix >= 0 && ix < TT) cnt += v_mask[iy * TT + ix];
        }
      w0[idx] = (cnt > 0.f) ? 1.f / fmaxf(cnt, 1.f) : 0.f;
    }
    __syncthreads();
    for (int idx = t; idx < DD * TT; idx += 256) {
      int y = idx / TT, x = idx % TT;
      float cnt = 0.f;
      for (int ky = 0; ky < 3; ++ky)
        for (int kx = 0; kx < 3; ++kx)
          cnt += (w0[(y + ky) * H1 + (x + kx)] > 0.f) ? 1.f : 0.f;
      w1[idx] = (cnt > 0.f) ? 1.f / fmaxf(cnt, 1.f) : 0.f;
    }
  }
}

// conv1: 1 output row per block (grid 66 x 8, 2 blocks/CU); 16x16x32 MFMA  (unchanged)
__global__ __launch_bounds__(256, 2) void conv1_mfma(
    const float* __restrict__ bc0, float* __restrict__ ws)
{
  const unsigned short* vT = (const unsigned short*)(ws + VT_OFF);
  const unsigned short* Bp = (const unsigned short*)(ws + BP0_OFF);
  const float* w0arr = ws + W0_OFF;
  unsigned short* y0w = (unsigned short*)(ws + Y0_OFF);

  __shared__ unsigned short Alds[3 * 68 * ASTR];   // 17952 B

  int t = threadIdx.x;
  int r0 = blockIdx.x;                 // output row 0..65
  int n = blockIdx.y;
  int lane = t & 63, w = t >> 6;       // w = co quarter
  int l15 = lane & 15, l4 = lane >> 4;
  int co0 = w * 32;

  f32x4 acc[5][2];
#pragma unroll
  for (int mf = 0; mf < 5; ++mf)
#pragma unroll
    for (int nf = 0; nf < 2; ++nf) acc[mf][nf] = (f32x4){0.f, 0.f, 0.f, 0.f};

  for (int cic = 0; cic < 4; ++cic) {
    __syncthreads();
    for (int u = t; u < 816; u += 256) {
      int cig = u & 3, rest = u >> 2;
      int col = rest % 68, r = rest / 68;
      int iy = r0 - 2 + r, ix = col - 2;
      uint4 val = {0u, 0u, 0u, 0u};
      if (iy >= 0 && iy < DD && ix >= 0 && ix < TT)
        val = *(const uint4*)&vT[(((size_t)(n * DD + iy) * TT + ix)) * CC + cic * 32 + cig * 8];
      *(uint4*)&Alds[(r * 68 + col) * ASTR + cig * 8] = val;
    }
    __syncthreads();
    __builtin_amdgcn_s_setprio(1);
#pragma unroll
    for (int kk = 0; kk < 9; ++kk) {
      int ky = kk / 3, kx = kk % 3;
      bf16x8 af[5], bfr[2];
#pragma unroll
      for (int mf = 0; mf < 5; ++mf) {
        int c = mf * 16 + l15;
        int cc = c > 65 ? 65 : c;
        af[mf] = *(const bf16x8*)&Alds[(ky * 68 + cc + kx) * ASTR + l4 * 8];
      }
#pragma unroll
      for (int nf = 0; nf < 2; ++nf)
        bfr[nf] = *(const bf16x8*)&Bp[(((kk * 4 + cic) * 8 + w * 2 + nf) * 64 + lane) * 8];
#pragma unroll
      for (int mf = 0; mf < 5; ++mf)
#pragma unroll
        for (int nf = 0; nf < 2; ++nf)
          acc[mf][nf] = __builtin_amdgcn_mfma_f32_16x16x32_bf16(af[mf], bfr[nf], acc[mf][nf], 0, 0, 0);
    }
    __builtin_amdgcn_s_setprio(0);
  }

  int y = r0;
#pragma unroll
  for (int nf = 0; nf < 2; ++nf) {
    int co = co0 + nf * 16 + l15;
    float bcv = bc0[co];
#pragma unroll
    for (int mf = 0; mf < 5; ++mf)
#pragma unroll
      for (int rg = 0; rg < 4; ++rg) {
        int c = mf * 16 + l4 * 4 + rg;
        if (c < H1) {
          float v = (acc[mf][nf][rg] + bcv) * w0arr[y * H1 + c];
          y0w[((size_t)(n * H1 + y) * H1 + c) * CC + co] = (unsigned short)cvt_bf(v);
        }
      }
  }
}

// conv2 R24: proven R20 staging + chunked B double-buffer in LDS.
// R23 proved (a) per-kk B global-load latency caps MfmaUtil at 33%, and
// (b) 1 block/CU is fatal. This keeps 2 blocks/CU: B staged in 2-kk slices
// (8KB per wc-half) double-buffered (32KB total; LDS ~70KB/block).
// Per cic: group g+1's 8 fire-and-forget DMAs issue before group g's 64 MFMA
// (~600cy covers ~300cy L2 latency); per-wave vmcnt(0)+sched_barrier (rule 18);
// raw s_barrier per group keeps the 4 waves lockstep so buffer recycling is
// safe; both wr waves of a wc issue IDENTICAL DMAs (same-value LDS race is
// benign, each wave's own vmcnt guards its own copy). Zero new persistent
// VGPRs (the spill law, 6 failures strong).
__global__ __launch_bounds__(256, 2) void conv2_mfma(
    const float* __restrict__ bc1, const float* __restrict__ W2d,
    const float* __restrict__ b2d, const float* __restrict__ v_mask,
    const int* __restrict__ valid_num, float* __restrict__ ws,
    float* __restrict__ out)
{
  const unsigned short* y0w = (const unsigned short*)(ws + Y0_OFF);
  const float* w1m = ws + W1_OFF;
  const float* g0 = ws + G0_OFF;
  const float* g1 = ws + G1_OFF;
  unsigned long long* scp = (unsigned long long*)(ws + SCP_OFF);

  __shared__ unsigned short Alds[6 * 66 * ASTR];   // 34848 B
  __shared__ unsigned short Blds[2][2][2][4][512]; // [wc][buf][kl][nf][512] = 32768 B
  __shared__ unsigned msk[16][4];                  // sign masks per (cic,cig)
  __shared__ float redl[2][4][64];
  __shared__ unsigned long long kred[4];

  int t = threadIdx.x;
  int r0 = blockIdx.x;                        // output rows r0*4 .. +3 (r0 in 0..15)
  int i = blockIdx.y & 7, n = blockIdx.y >> 3;   // n-major: L2 locality on y0w[n]
  int lane = t & 63, w = t >> 6;
  int wr = w >> 1, wc = w & 1;
  int l15 = lane & 15, l4 = lane >> 4;

  const unsigned short* Bp = (const unsigned short*)(ws + BP1S_OFF) + (size_t)i * 147456;

  if (t < 16) {                               // t = cic*4+cig -> channels t*8..t*8+7
    int ch = t * 8;
    msk[t][0] = (g0[i * CC + ch + 0] > 0.f ? 0u : 0x8000u) | (g0[i * CC + ch + 1] > 0.f ? 0u : 0x80000000u);
    msk[t][1] = (g0[i * CC + ch + 2] > 0.f ? 0u : 0x8000u) | (g0[i * CC + ch + 3] > 0.f ? 0u : 0x80000000u);
    msk[t][2] = (g0[i * CC + ch + 4] > 0.f ? 0u : 0x8000u) | (g0[i * CC + ch + 5] > 0.f ? 0u : 0x80000000u);
    msk[t][3] = (g0[i * CC + ch + 6] > 0.f ? 0u : 0x8000u) | (g0[i * CC + ch + 7] > 0.f ? 0u : 0x80000000u);
  }

  f32x4 acc[8][4];
#pragma unroll
  for (int mf = 0; mf < 8; ++mf)
#pragma unroll
    for (int nf = 0; nf < 4; ++nf) acc[mf][nf] = (f32x4){0.f, 0.f, 0.f, 0.f};

  for (int cic = 0; cic < 4; ++cic) {
    __syncthreads();   // prev MFMA's LDS reads consumed

    // issue B group0 (kk 0,1) DMAs for this cic into buf0 (zero live VGPRs)
#pragma unroll
    for (int kl = 0; kl < 2; ++kl)
#pragma unroll
      for (int nf = 0; nf < 4; ++nf)
        dma16((const char*)Bp + (((kl * 4 + cic) * 8 + wc * 4 + nf) * 64 + lane) * 16,
              &Blds[wc][0][kl][nf][0]);

    // stage A: 6 rows x 66 cols x 32ci, selbf sign-select (PROVEN, unchanged)
    {
      uint4 mv = *(const uint4*)&msk[(cic << 2) | (t & 3)][0];
      for (int u = t; u < 1584; u += 256) {
        int cig = u & 3, cr = u >> 2;
        int col = cr % 66, row = cr / 66;       // row 0..5
        const unsigned short* src = y0w
            + ((size_t)((n * H1 + r0 * 4 + row) * H1 + col)) * CC + cic * 32 + cig * 8;
        uint4 raw = *(const uint4*)src;
        uint4 pk;
        pk.x = selbf(raw.x, mv.x);
        pk.y = selbf(raw.y, mv.y);
        pk.z = selbf(raw.z, mv.z);
        pk.w = selbf(raw.w, mv.w);
        *(uint4*)&Alds[(row * 66 + col) * ASTR + cig * 8] = pk;
      }
    }
    __syncthreads();   // A ready; full vmcnt drain => B group0 landed too

    __builtin_amdgcn_s_setprio(1);
#pragma unroll
    for (int g = 0; g < 5; ++g) {              // kk groups {0,1}{2,3}{4,5}{6,7}{8}
      __builtin_amdgcn_s_barrier();            // lockstep: buf (g+1)&1 free to overwrite
      if (g < 4) {                             // issue next group's DMAs
        const int nk0 = (g + 1) * 2;
        const int nsz = (g + 1 == 4) ? 1 : 2;
        const int nb = (g + 1) & 1;
#pragma unroll
        for (int kl = 0; kl < 2; ++kl) {
          if (kl < nsz) {
#pragma unroll
            for (int nf = 0; nf < 4; ++nf)
              dma16((const char*)Bp + ((((nk0 + kl) * 4 + cic) * 8 + wc * 4 + nf) * 64 + lane) * 16,
                    &Blds[wc][nb][kl][nf][0]);
          }
        }
      }
      const int ksz = (g == 4) ? 1 : 2;
#pragma unroll
      for (int kl = 0; kl < 2; ++kl) {
        if (kl < ksz) {
          int kk = g * 2 + kl;
          int ky = kk / 3, kx = kk % 3;
          bf16x8 af[8], bfr[4];
#pragma unroll
          for (int mf = 0; mf < 8; ++mf) {
            int row = wr * 2 + (mf >> 2) + ky;          // 0..5
            int col = (mf & 3) * 16 + l15 + kx;         // 0..65
            af[mf] = *(const bf16x8*)&Alds[(row * 66 + col) * ASTR + l4 * 8];
          }
#pragma unroll
          for (int nf = 0; nf < 4; ++nf)
            bfr[nf] = *(const bf16x8*)&Blds[wc][g & 1][kl][nf][lane * 8];
#pragma unroll
          for (int mf = 0; mf < 8; ++mf)
#pragma unroll
            for (int nf = 0; nf < 4; ++nf)
              acc[mf][nf] = __builtin_amdgcn_mfma_f32_16x16x32_bf16(af[mf], bfr[nf], acc[mf][nf], 0, 0, 0);
        }
      }
      if (g < 4) {                             // own next-group DMAs landed
        asm volatile("s_waitcnt vmcnt(0)" ::: "memory");
        __builtin_amdgcn_sched_barrier(0);
      }
    }
    __builtin_amdgcn_s_setprio(0);
  }

  // epilogue: relu((acc+bc1)*g1)*W2d, reduce over co; weight1 factored out (w1>=0)
  float part[8][4];
#pragma unroll
  for (int mf = 0; mf < 8; ++mf)
#pragma unroll
    for (int rg = 0; rg < 4; ++rg) part[mf][rg] = 0.f;
#pragma unroll
  for (int nf = 0; nf < 4; ++nf) {
    int co = wc * 64 + nf * 16 + l15;
    float bcv = bc1[co];
    float gv = g1[i * CC + co];
    float wv = W2d[co];
#pragma unroll
    for (int mf = 0; mf < 8; ++mf)
#pragma unroll
      for (int rg = 0; rg < 4; ++rg) {
        float z = (acc[mf][nf][rg] + bcv) * gv;
        part[mf][rg] += fmaxf(z, 0.f) * wv;
      }
  }
#pragma unroll
  for (int mask = 1; mask < 16; mask <<= 1)
#pragma unroll
    for (int mf = 0; mf < 8; ++mf)
#pragma unroll
      for (int rg = 0; rg < 4; ++rg)
        part[mf][rg] += __shfl_xor(part[mf][rg], mask, 64);
  if (l15 == 0) {
#pragma unroll
    for (int mf = 0; mf < 8; ++mf)
#pragma unroll
      for (int rg = 0; rg < 4; ++rg)
        redl[wc][wr * 2 + (mf >> 2)][(mf & 3) * 16 + l4 * 4 + rg] = part[mf][rg];
  }
  __syncthreads();
  {
    int row = t >> 6, col = t & 63;
    int rowg = r0 * 4 + row;
    float v = redl[0][row][col] + redl[1][row][col];
    float logit = w1m[rowg * TT + col] * v + b2d[0];
    float sig = 1.f / (1.f + expf(-logit));
    bool m = (v_mask[rowg * TT + col] > 0.f) && (col < valid_num[n]);
    int p = rowg * TT + col;
    if (i == n) {
      ws[S_OFF + i * PP + p] = m ? sig : -INFINITY;           // for hard-neg mining
      out[1 + i * PP + p] = m ? sig : NEG_SENTINEL;           // positive_map output
    }
    unsigned long long key = 0ull;
    if (m) key = ((unsigned long long)__float_as_uint(sig) << 32)
                 | (unsigned long long)(0xFFFFFFFFu - (unsigned)p);
#pragma unroll
    for (int mk = 1; mk < 64; mk <<= 1) {
      unsigned lo = __shfl_xor((unsigned)key, mk, 64);
      unsigned hi = __shfl_xor((unsigned)(key >> 32), mk, 64);
      unsigned long long o = ((unsigned long long)hi << 32) | lo;
      if (o > key) key = o;
    }
    if (lane == 0) kred[w] = key;
  }
  __syncthreads();
  if (t == 0) {
    unsigned long long k = kred[0];
    if (kred[1] > k) k = kred[1];
    if (kred[2] > k) k = kred[2];
    if (kred[3] > k) k = kred[3];
    if (k) atomicMax(&scp[i * 8 + n], k);
  }
}

// hard-negative mining: one block per sentence (8 blocks x 256 thr)
__global__ __launch_bounds__(256) void mine_kernel(
    const float* __restrict__ iou_maps, const float* __restrict__ lam,
    float* __restrict__ ws)
{
  __shared__ float wred[4];
  int i = blockIdx.x;
  int t = threadIdx.x, lane = t & 63, w = t >> 6;
  const unsigned long long* scp = (const unsigned long long*)(ws + SCP_OFF);

  unsigned long long dk = scp[i * 9];                  // diag (i,i)
  float diag_sc = __uint_as_float((unsigned)(dk >> 32));
  int pidx = (int)(0xFFFFFFFFu - (unsigned)(dk & 0xFFFFFFFFu));
  float lamv = lam[0];
  const float* row = iou_maps + (size_t)pidx * PP;
  const float* si = ws + S_OFF + (size_t)i * PP;
  float hv = -INFINITY;
  for (int p = t; p < PP; p += 256) {
    float v = si[p];
    if (row[p] < lamv && isfinite(v)) hv = fmaxf(hv, v);
  }
#pragma unroll
  for (int m = 1; m < 64; m <<= 1) hv = fmaxf(hv, __shfl_xor(hv, m, 64));
  if (lane == 0) wred[w] = hv;
  __syncthreads();
  if (t == 0) {
    float h = fmaxf(fmaxf(wred[0], wred[1]), fmaxf(wred[2], wred[3]));
    ws[NL_OFF + i] = fmaxf(0.f, MARGINF + h - diag_sc);
  }
}

// final loss: 1 wave, sorting-network top-3 (unchanged math)
__global__ __launch_bounds__(64) void loss_kernel(
    float* __restrict__ ws, float* __restrict__ out)
{
  __shared__ float scsh[64];
  int lane = threadIdx.x;
  const unsigned long long* scp = (const unsigned long long*)(ws + SCP_OFF);
  scsh[lane] = __uint_as_float((unsigned)(scp[lane] >> 32));
  __syncthreads();

  float partial = 0.f;
  if (lane < 16) {
    int r = lane & 7;
    bool im = lane >= 8;
    float diag = scsh[r * 8 + r];
    float v[8];
#pragma unroll
    for (int j = 0; j < 8; ++j) {
      float scv = im ? scsh[j * 8 + r] : scsh[r * 8 + j];
      float h = fmaxf(0.f, MARGINF + scv - diag);
      v[j] = (j == r) ? 0.f : h;
    }
#define CE(a, b) { float mx = fmaxf(v[a], v[b]); float mn = fminf(v[a], v[b]); v[a] = mx; v[b] = mn; }
    CE(0,1) CE(2,3) CE(4,5) CE(6,7)
    CE(0,2) CE(1,3) CE(4,6) CE(5,7)
    CE(1,2) CE(5,6)
    CE(0,4) CE(1,5) CE(2,6) CE(3,7)
    CE(2,4) CE(3,5)
    CE(1,2) CE(3,4) CE(5,6)
#undef CE
    partial = v[0] + v[1] + v[2];
  } else if (lane >= 16 && lane < 24) {
    partial = ws[NL_OFF + lane - 16];
  }
#pragma unroll
  for (int m = 1; m < 64; m <<= 1) partial += __shfl_xor(partial, m, 64);
  if (lane == 0) out[0] = partial * 0.125f;
}

extern "C" void kernel_launch(void* const* d_in, const int* in_sizes, int n_in,
                              void* d_out, int out_size, void* d_ws, size_t ws_size,
                              hipStream_t stream)
{
  const float* v_map     = (const float*)d_in[0];
  const float* words     = (const float*)d_in[1];
  const float* w_masks   = (const float*)d_in[2];
  const float* v_mask    = (const float*)d_in[3];
  const int*   valid_num = (const int*)d_in[4];
  const float* iou_maps  = (const float*)d_in[5];
  const float* lam       = (const float*)d_in[6];
  const float* Wc0 = (const float*)d_in[7];
  const float* bc0 = (const float*)d_in[8];
  const float* Wc1 = (const float*)d_in[9];
  const float* bc1 = (const float*)d_in[10];
  const float* Wp0 = (const float*)d_in[11];
  const float* bp0 = (const float*)d_in[12];
  const float* Wp1 = (const float*)d_in[13];
  const float* bp1 = (const float*)d_in[14];
  const float* W2d = (const float*)d_in[15];
  const float* b2d = (const float*)d_in[16];
  float* ws  = (float*)d_ws;
  float* out = (float*)d_out;

  hipLaunchKernelGGL(gates_kernel, dim3(8), dim3(256), 0, stream,
                     words, w_masks, Wp0, bp0, Wp1, bp1, ws);
  hipLaunchKernelGGL(setup_kernel, dim3(1665), dim3(256), 0, stream,
                     v_map, v_mask, Wc0, Wc1, ws);
  hipLaunchKernelGGL(conv1_mfma, dim3(66, 8), dim3(256), 0, stream, bc0, ws);
  hipLaunchKernelGGL(conv2_mfma, dim3(16, 64), dim3(256), 0, stream,
                     bc1, W2d, b2d, v_mask, valid_num, ws, out);
  hipLaunchKernelGGL(mine_kernel, dim3(8), dim3(256), 0, stream, iou_maps, lam, ws);
  hipLaunchKernelGGL(loss_kernel, dim3(1), dim3(64), 0, stream, ws, out);
}

// Round 9
// 147.570 us; speedup vs baseline: 1.2002x; 1.0116x over previous
//
#include <hip/hip_runtime.h>
#include <hip/hip_bf16.h>
#include <math.h>

#define BB 8
#define CC 128
#define DD 64
#define TT 64
#define PP 4096
#define H1 66
#define LW 20
#define MARGINF 0.1f
#define NEG_SENTINEL -1.0e30f

// workspace layout (float offsets)
#define Y0_OFF   0            // y0w bf16 channel-last [8][66][66][128] = 2230272 f
#define VT_OFF   2230272      // vT bf16 [8][64][64][128] = 2097152 f
#define BP0_OFF  4327424      // Bpack(Wc0) 16x16 layout = 73728 f
#define NL_OFF   4401152      // per-sentence neg-loss [8] (old BP1 slot, unused gap)
#define W0_OFF   4479236      // weight0 [66][66] = 4356
#define W1_OFF   4483592      // weight1 [64][64] = 4096
#define G0_OFF   4487688      // [8][128]
#define G1_OFF   4488712      // [8][128]
#define S_OFF    4489736      // si [8][4096] = 32768 (diag maps only)
#define SCP_OFF  4522504      // packed scores u64 [64] = 128 f
#define BP1S_OFF 4522632      // 8x gate-scaled Bpack(Wc1*g0[i]) = 8*73728 f = 589824 f
// total ≈ 5112456 floats ≈ 20.5 MB

typedef __attribute__((ext_vector_type(8))) short bf16x8;
typedef __attribute__((ext_vector_type(4))) float f32x4;

// LDS (row,col) stride in shorts: 44 (=88B), conflict-light b128 access
#define ASTR 44

__device__ __forceinline__ unsigned f2bf(float f) {
  union { float f; unsigned u; } v; v.f = f;
  unsigned r = v.u + 0x7fffu + ((v.u >> 16) & 1u);   // RNE (setup only)
  return r >> 16;
}
__device__ __forceinline__ float bf2f(unsigned hw) {
  union { unsigned u; float f; } v; v.u = hw << 16;
  return v.f;
}
// native cast: compiler emits v_cvt_pk for pairs (m240)
__device__ __forceinline__ unsigned cvt_bf(float x) {
  __hip_bfloat16 h = __float2bfloat16(x);
  union { __hip_bfloat16 h; unsigned short u; } cv; cv.h = h;
  return (unsigned)cv.u;
}

// sign-select on 2 packed bf16: keep half iff sign(v) == wanted sign bit in W.
// relu(g*v)*Wc1 == select(v) * (Wc1*g), select(v) = g>0 ? max(v,0) : min(v,0)
__device__ __forceinline__ unsigned selbf(unsigned d, unsigned W) {
  unsigned diff = (d ^ W) & 0x80008000u;     // sign mismatch bits
  unsigned full = (diff >> 15) * 0xFFFFu;    // expand to half-word masks
  return d & ~full;                          // zero mismatched halves
}

// ---------------- gates: pooled words -> g0,g1 (must precede setup: B1 pack needs g0)
__global__ __launch_bounds__(256) void gates_kernel(
    const float* __restrict__ words, const float* __restrict__ w_masks,
    const float* __restrict__ Wp0, const float* __restrict__ bp0,
    const float* __restrict__ Wp1, const float* __restrict__ bp1,
    float* __restrict__ ws)
{
  __shared__ float smem[CC];
  int i = blockIdx.x;
  int t = threadIdx.x;
  if (t < CC) {
    float wsum = 0.f, acc = 0.f;
    for (int l = 0; l < LW; ++l) {
      float wm = w_masks[i * LW + l];
      wsum += wm;
      acc += words[(i * LW + l) * CC + t] * wm;
    }
    smem[t] = acc / fmaxf(wsum, 1.f);
  }
  __syncthreads();
  {
    int c = t & 127;
    const float* Wp = (t < 128) ? Wp0 : Wp1;
    const float* bp = (t < 128) ? bp0 : bp1;
    float a = bp[c];
    for (int k = 0; k < CC; ++k) a += smem[k] * Wp[k * CC + c];
    float g = tanhf(a);
    float* gout = ws + ((t < 128) ? G0_OFF : G1_OFF);
    gout[i * CC + c] = g;
  }
}

// ---------------- fused setup: pack B0, pack B1 x8 (one-read-eight-writes),
// transpose (XCD-aligned: vT[n] written on XCD n), w0/w1, scp zero
__global__ __launch_bounds__(256) void setup_kernel(
    const float* __restrict__ vmap, const float* __restrict__ v_mask,
    const float* __restrict__ Wc0, const float* __restrict__ Wc1,
    float* __restrict__ ws)
{
  __shared__ float smem[64 * 129];
  int bid = blockIdx.x;
  int t = threadIdx.x;

  if (bid < 576) {
    // B0 pack (unscaled)
    unsigned short* dst = (unsigned short*)(ws + BP0_OFF);
    int idx = bid * 256 + t;
    int j    = idx & 7;
    int lane = (idx >> 3) & 63;
    int cog  = (idx >> 9) & 7;
    int cic  = (idx >> 12) & 3;
    int kk   = idx >> 14;
    int co = cog * 16 + (lane & 15);
    int ci = cic * 32 + (lane >> 4) * 8 + j;
    dst[idx] = (unsigned short)f2bf(Wc0[(co * CC + ci) * 9 + kk]);
  } else if (bid < 1152) {
    // B1S pack: read each Wc1 element ONCE, write 8 gate-scaled copies
    for (int v = t; v < 8 * CC; v += 256) smem[v] = ws[G0_OFF + v];
    __syncthreads();
    int idx = (bid - 576) * 256 + t;
    int j    = idx & 7;
    int lane = (idx >> 3) & 63;
    int cog  = (idx >> 9) & 7;
    int cic  = (idx >> 12) & 3;
    int kk   = idx >> 14;
    int co = cog * 16 + (lane & 15);
    int ci = cic * 32 + (lane >> 4) * 8 + j;
    float wv = Wc1[(co * CC + ci) * 9 + kk];
    unsigned short* dst = (unsigned short*)(ws + BP1S_OFF);
#pragma unroll
    for (int si = 0; si < 8; ++si)
      dst[si * 147456 + idx] = (unsigned short)f2bf(wv * smem[si * CC + ci]);
  } else if (bid < 1664) {
    unsigned short* vT = (unsigned short*)(ws + VT_OFF);
    int b = bid - 1152;                  // 1152 % 8 == 0 -> XCD = b & 7
    int n = b & 7, y = b >> 3;           // XCD-aligned: vT[n] stays in XCD n's L2
    int x = t & 63, c4 = t >> 6;
    for (int rep = 0; rep < 32; ++rep) {
      int ci = rep * 4 + c4;
      smem[x * 129 + ci] = vmap[(((size_t)n * CC + ci) * DD + y) * TT + x];
    }
    __syncthreads();
    for (int rep = 0; rep < 16; ++rep) {
      int v = t + rep * 256;
      int xx = v >> 6, cip = v & 63;
      float a = smem[xx * 129 + cip * 2];
      float b2 = smem[xx * 129 + cip * 2 + 1];
      unsigned pk = f2bf(a) | (f2bf(b2) << 16);
      *(unsigned*)&vT[(((size_t)(n * DD + y) * TT + xx)) * CC + cip * 2] = pk;
    }
  } else {
    if (t < 128) ((unsigned*)(ws + SCP_OFF))[t] = 0u;   // zero packed scores
    float* w0 = ws + W0_OFF;
    float* w1 = ws + W1_OFF;
    for (int idx = t; idx < H1 * H1; idx += 256) {
      int y = idx / H1, x = idx % H1;
      float cnt = 0.f;
      for (int ky = 0; ky < 3; ++ky)
        for (int kx = 0; kx < 3; ++kx) {
          int iy = y + ky - 2, ix = x + kx - 2;
          if (iy >= 0 && iy < DD && ix >= 0 && ix < TT) cnt += v_mask[iy * TT + ix];
        }
      w0[idx] = (cnt > 0.f) ? 1.f / fmaxf(cnt, 1.f) : 0.f;
    }
    __syncthreads();
    for (int idx = t; idx < DD * TT; idx += 256) {
      int y = idx / TT, x = idx % TT;
      float cnt = 0.f;
      for (int ky = 0; ky < 3; ++ky)
        for (int kx = 0; kx < 3; ++kx)
          cnt += (w0[(y + ky) * H1 + (x + kx)] > 0.f) ? 1.f : 0.f;
      w1[idx] = (cnt > 0.f) ? 1.f / fmaxf(cnt, 1.f) : 0.f;
    }
  }
}

// conv1: XCD-aligned n = id&7 (reads vT[n] written on XCD n; writes y0w[n]
// which conv2 on XCD n will read — whole n-chain stays in one XCD's L2)
__global__ __launch_bounds__(256, 2) void conv1_mfma(
    const float* __restrict__ bc0, float* __restrict__ ws)
{
  const unsigned short* vT = (const unsigned short*)(ws + VT_OFF);
  const unsigned short* Bp = (const unsigned short*)(ws + BP0_OFF);
  const float* w0arr = ws + W0_OFF;
  unsigned short* y0w = (unsigned short*)(ws + Y0_OFF);

  __shared__ unsigned short Alds[3 * 68 * ASTR];   // 17952 B

  int t = threadIdx.x;
  int id = blockIdx.x + 66 * blockIdx.y;   // 0..527
  int n  = id & 7;                         // XCD-aligned
  int r0 = id >> 3;                        // output row 0..65
  int lane = t & 63, w = t >> 6;           // w = co quarter
  int l15 = lane & 15, l4 = lane >> 4;
  int co0 = w * 32;

  f32x4 acc[5][2];
#pragma unroll
  for (int mf = 0; mf < 5; ++mf)
#pragma unroll
    for (int nf = 0; nf < 2; ++nf) acc[mf][nf] = (f32x4){0.f, 0.f, 0.f, 0.f};

  for (int cic = 0; cic < 4; ++cic) {
    __syncthreads();
    for (int u = t; u < 816; u += 256) {
      int cig = u & 3, rest = u >> 2;
      int col = rest % 68, r = rest / 68;
      int iy = r0 - 2 + r, ix = col - 2;
      uint4 val = {0u, 0u, 0u, 0u};
      if (iy >= 0 && iy < DD && ix >= 0 && ix < TT)
        val = *(const uint4*)&vT[(((size_t)(n * DD + iy) * TT + ix)) * CC + cic * 32 + cig * 8];
      *(uint4*)&Alds[(r * 68 + col) * ASTR + cig * 8] = val;
    }
    __syncthreads();
    __builtin_amdgcn_s_setprio(1);
#pragma unroll
    for (int kk = 0; kk < 9; ++kk) {
      int ky = kk / 3, kx = kk % 3;
      bf16x8 af[5], bfr[2];
#pragma unroll
      for (int mf = 0; mf < 5; ++mf) {
        int c = mf * 16 + l15;
        int cc = c > 65 ? 65 : c;
        af[mf] = *(const bf16x8*)&Alds[(ky * 68 + cc + kx) * ASTR + l4 * 8];
      }
#pragma unroll
      for (int nf = 0; nf < 2; ++nf)
        bfr[nf] = *(const bf16x8*)&Bp[(((kk * 4 + cic) * 8 + w * 2 + nf) * 64 + lane) * 8];
#pragma unroll
      for (int mf = 0; mf < 5; ++mf)
#pragma unroll
        for (int nf = 0; nf < 2; ++nf)
          acc[mf][nf] = __builtin_amdgcn_mfma_f32_16x16x32_bf16(af[mf], bfr[nf], acc[mf][nf], 0, 0, 0);
    }
    __builtin_amdgcn_s_setprio(0);
  }

  int y = r0;
#pragma unroll
  for (int nf = 0; nf < 2; ++nf) {
    int co = co0 + nf * 16 + l15;
    float bcv = bc0[co];
#pragma unroll
    for (int mf = 0; mf < 5; ++mf)
#pragma unroll
      for (int rg = 0; rg < 4; ++rg) {
        int c = mf * 16 + l4 * 4 + rg;
        if (c < H1) {
          float v = (acc[mf][nf][rg] + bcv) * w0arr[y * H1 + c];
          y0w[((size_t)(n * H1 + y) * H1 + c) * CC + co] = (unsigned short)cvt_bf(v);
        }
      }
  }
}

// conv2: proven R20/R22 structure (2-barrier loop, selbf staging, ASTR layout)
// + XCD-aligned remap: n = id&7 so XCD k reads ONLY y0w[k] — which conv1 on
// XCD k just wrote (dirty in its L2). Staging loads go from ~900cy HBM to
// ~200cy L2, shrinking the serial staging chain 4.5x. i = rest>>4 keeps the
// resident BP1S working set at ~4 slices (~4.7MB ~ L2). Zero new registers.
__global__ __launch_bounds__(256, 2) void conv2_mfma(
    const float* __restrict__ bc1, const float* __restrict__ W2d,
    const float* __restrict__ b2d, const float* __restrict__ v_mask,
    const int* __restrict__ valid_num, float* __restrict__ ws,
    float* __restrict__ out)
{
  const unsigned short* y0w = (const unsigned short*)(ws + Y0_OFF);
  const float* w1m = ws + W1_OFF;
  const float* g0 = ws + G0_OFF;
  const float* g1 = ws + G1_OFF;
  unsigned long long* scp = (unsigned long long*)(ws + SCP_OFF);

  __shared__ unsigned short Alds[6 * 66 * ASTR];   // 34848 B
  __shared__ unsigned msk[16][4];                  // sign masks per (cic,cig)
  __shared__ float redl[2][4][64];
  __shared__ unsigned long long kred[4];

  int t = threadIdx.x;
  int id = blockIdx.x + (blockIdx.y << 4);    // 0..1023
  int n  = id & 7;                            // XCD-aligned video
  int rest = id >> 3;
  int i  = rest >> 4;                         // sentence 0..7 (stable per 16 ids)
  int r0 = rest & 15;                         // output rows r0*4 .. +3
  int lane = t & 63, w = t >> 6;
  int wr = w >> 1, wc = w & 1;
  int l15 = lane & 15, l4 = lane >> 4;

  const unsigned short* Bp = (const unsigned short*)(ws + BP1S_OFF) + (size_t)i * 147456;

  if (t < 16) {                               // t = cic*4+cig -> channels t*8..t*8+7
    int ch = t * 8;
    msk[t][0] = (g0[i * CC + ch + 0] > 0.f ? 0u : 0x8000u) | (g0[i * CC + ch + 1] > 0.f ? 0u : 0x80000000u);
    msk[t][1] = (g0[i * CC + ch + 2] > 0.f ? 0u : 0x8000u) | (g0[i * CC + ch + 3] > 0.f ? 0u : 0x80000000u);
    msk[t][2] = (g0[i * CC + ch + 4] > 0.f ? 0u : 0x8000u) | (g0[i * CC + ch + 5] > 0.f ? 0u : 0x80000000u);
    msk[t][3] = (g0[i * CC + ch + 6] > 0.f ? 0u : 0x8000u) | (g0[i * CC + ch + 7] > 0.f ? 0u : 0x80000000u);
  }

  f32x4 acc[8][4];
#pragma unroll
  for (int mf = 0; mf < 8; ++mf)
#pragma unroll
    for (int nf = 0; nf < 4; ++nf) acc[mf][nf] = (f32x4){0.f, 0.f, 0.f, 0.f};

  for (int cic = 0; cic < 4; ++cic) {
    __syncthreads();
    // stage 6 rows x 66 cols x 32ci: 1584 uint4s; select applied via sign bits
    {
      uint4 mv = *(const uint4*)&msk[(cic << 2) | (t & 3)][0];
      for (int u = t; u < 1584; u += 256) {
        int cig = u & 3, cr = u >> 2;
        int col = cr % 66, row = cr / 66;       // row 0..5
        const unsigned short* src = y0w
            + ((size_t)((n * H1 + r0 * 4 + row) * H1 + col)) * CC + cic * 32 + cig * 8;
        uint4 raw = *(const uint4*)src;
        uint4 pk;
        pk.x = selbf(raw.x, mv.x);
        pk.y = selbf(raw.y, mv.y);
        pk.z = selbf(raw.z, mv.z);
        pk.w = selbf(raw.w, mv.w);
        *(uint4*)&Alds[(row * 66 + col) * ASTR + cig * 8] = pk;
      }
    }
    __syncthreads();
    __builtin_amdgcn_s_setprio(1);
#pragma unroll
    for (int kk = 0; kk < 9; ++kk) {
      int ky = kk / 3, kx = kk % 3;
      bf16x8 af[8], bfr[4];
#pragma unroll
      for (int mf = 0; mf < 8; ++mf) {
        int row = wr * 2 + (mf >> 2) + ky;          // 0..5
        int col = (mf & 3) * 16 + l15 + kx;         // 0..65
        af[mf] = *(const bf16x8*)&Alds[(row * 66 + col) * ASTR + l4 * 8];
      }
#pragma unroll
      for (int nf = 0; nf < 4; ++nf)
        bfr[nf] = *(const bf16x8*)&Bp[(((kk * 4 + cic) * 8 + wc * 4 + nf) * 64 + lane) * 8];
#pragma unroll
      for (int mf = 0; mf < 8; ++mf)
#pragma unroll
        for (int nf = 0; nf < 4; ++nf)
          acc[mf][nf] = __builtin_amdgcn_mfma_f32_16x16x32_bf16(af[mf], bfr[nf], acc[mf][nf], 0, 0, 0);
    }
    __builtin_amdgcn_s_setprio(0);
  }

  // epilogue: relu((acc+bc1)*g1)*W2d, reduce over co; weight1 factored out (w1>=0)
  float part[8][4];
#pragma unroll
  for (int mf = 0; mf < 8; ++mf)
#pragma unroll
    for (int rg = 0; rg < 4; ++rg) part[mf][rg] = 0.f;
#pragma unroll
  for (int nf = 0; nf < 4; ++nf) {
    int co = wc * 64 + nf * 16 + l15;
    float bcv = bc1[co];
    float gv = g1[i * CC + co];
    float wv = W2d[co];
#pragma unroll
    for (int mf = 0; mf < 8; ++mf)
#pragma unroll
      for (int rg = 0; rg < 4; ++rg) {
        float z = (acc[mf][nf][rg] + bcv) * gv;
        part[mf][rg] += fmaxf(z, 0.f) * wv;
      }
  }
#pragma unroll
  for (int mask = 1; mask < 16; mask <<= 1)
#pragma unroll
    for (int mf = 0; mf < 8; ++mf)
#pragma unroll
      for (int rg = 0; rg < 4; ++rg)
        part[mf][rg] += __shfl_xor(part[mf][rg], mask, 64);
  if (l15 == 0) {
#pragma unroll
    for (int mf = 0; mf < 8; ++mf)
#pragma unroll
      for (int rg = 0; rg < 4; ++rg)
        redl[wc][wr * 2 + (mf >> 2)][(mf & 3) * 16 + l4 * 4 + rg] = part[mf][rg];
  }
  __syncthreads();
  {
    int row = t >> 6, col = t & 63;
    int rowg = r0 * 4 + row;
    float v = redl[0][row][col] + redl[1][row][col];
    float logit = w1m[rowg * TT + col] * v + b2d[0];
    float sig = 1.f / (1.f + expf(-logit));
    bool m = (v_mask[rowg * TT + col] > 0.f) && (col < valid_num[n]);
    int p = rowg * TT + col;
    if (i == n) {
      ws[S_OFF + i * PP + p] = m ? sig : -INFINITY;           // for hard-neg mining
      out[1 + i * PP + p] = m ? sig : NEG_SENTINEL;           // positive_map output
    }
    unsigned long long key = 0ull;
    if (m) key = ((unsigned long long)__float_as_uint(sig) << 32)
                 | (unsigned long long)(0xFFFFFFFFu - (unsigned)p);
#pragma unroll
    for (int mk = 1; mk < 64; mk <<= 1) {
      unsigned lo = __shfl_xor((unsigned)key, mk, 64);
      unsigned hi = __shfl_xor((unsigned)(key >> 32), mk, 64);
      unsigned long long o = ((unsigned long long)hi << 32) | lo;
      if (o > key) key = o;
    }
    if (lane == 0) kred[w] = key;
  }
  __syncthreads();
  if (t == 0) {
    unsigned long long k = kred[0];
    if (kred[1] > k) k = kred[1];
    if (kred[2] > k) k = kred[2];
    if (kred[3] > k) k = kred[3];
    if (k) atomicMax(&scp[i * 8 + n], k);
  }
}

// hard-negative mining: one block per sentence (8 blocks x 256 thr)
__global__ __launch_bounds__(256) void mine_kernel(
    const float* __restrict__ iou_maps, const float* __restrict__ lam,
    float* __restrict__ ws)
{
  __shared__ float wred[4];
  int i = blockIdx.x;
  int t = threadIdx.x, lane = t & 63, w = t >> 6;
  const unsigned long long* scp = (const unsigned long long*)(ws + SCP_OFF);

  unsigned long long dk = scp[i * 9];                  // diag (i,i)
  float diag_sc = __uint_as_float((unsigned)(dk >> 32));
  int pidx = (int)(0xFFFFFFFFu - (unsigned)(dk & 0xFFFFFFFFu));
  float lamv = lam[0];
  const float* row = iou_maps + (size_t)pidx * PP;
  const float* si = ws + S_OFF + (size_t)i * PP;
  float hv = -INFINITY;
  for (int p = t; p < PP; p += 256) {
    float v = si[p];
    if (row[p] < lamv && isfinite(v)) hv = fmaxf(hv, v);
  }
#pragma unroll
  for (int m = 1; m < 64; m <<= 1) hv = fmaxf(hv, __shfl_xor(hv, m, 64));
  if (lane == 0) wred[w] = hv;
  __syncthreads();
  if (t == 0) {
    float h = fmaxf(fmaxf(wred[0], wred[1]), fmaxf(wred[2], wred[3]));
    ws[NL_OFF + i] = fmaxf(0.f, MARGINF + h - diag_sc);
  }
}

// final loss: 1 wave, sorting-network top-3 (unchanged math)
__global__ __launch_bounds__(64) void loss_kernel(
    float* __restrict__ ws, float* __restrict__ out)
{
  __shared__ float scsh[64];
  int lane = threadIdx.x;
  const unsigned long long* scp = (const unsigned long long*)(ws + SCP_OFF);
  scsh[lane] = __uint_as_float((unsigned)(scp[lane] >> 32));
  __syncthreads();

  float partial = 0.f;
  if (lane < 16) {
    int r = lane & 7;
    bool im = lane >= 8;
    float diag = scsh[r * 8 + r];
    float v[8];
#pragma unroll
    for (int j = 0; j < 8; ++j) {
      float scv = im ? scsh[j * 8 + r] : scsh[r * 8 + j];
      float h = fmaxf(0.f, MARGINF + scv - diag);
      v[j] = (j == r) ? 0.f : h;
    }
#define CE(a, b) { float mx = fmaxf(v[a], v[b]); float mn = fminf(v[a], v[b]); v[a] = mx; v[b] = mn; }
    CE(0,1) CE(2,3) CE(4,5) CE(6,7)
    CE(0,2) CE(1,3) CE(4,6) CE(5,7)
    CE(1,2) CE(5,6)
    CE(0,4) CE(1,5) CE(2,6) CE(3,7)
    CE(2,4) CE(3,5)
    CE(1,2) CE(3,4) CE(5,6)
#undef CE
    partial = v[0] + v[1] + v[2];
  } else if (lane >= 16 && lane < 24) {
    partial = ws[NL_OFF + lane - 16];
  }
#pragma unroll
  for (int m = 1; m < 64; m <<= 1) partial += __shfl_xor(partial, m, 64);
  if (lane == 0) out[0] = partial * 0.125f;
}

extern "C" void kernel_launch(void* const* d_in, const int* in_sizes, int n_in,
                              void* d_out, int out_size, void* d_ws, size_t ws_size,
                              hipStream_t stream)
{
  const float* v_map     = (const float*)d_in[0];
  const float* words     = (const float*)d_in[1];
  const float* w_masks   = (const float*)d_in[2];
  const float* v_mask    = (const float*)d_in[3];
  const int*   valid_num = (const int*)d_in[4];
  const float* iou_maps  = (const float*)d_in[5];
  const float* lam       = (const float*)d_in[6];
  const float* Wc0 = (const float*)d_in[7];
  const float* bc0 = (const float*)d_in[8];
  const float* Wc1 = (const float*)d_in[9];
  const float* bc1 = (const float*)d_in[10];
  const float* Wp0 = (const float*)d_in[11];
  const float* bp0 = (const float*)d_in[12];
  const float* Wp1 = (const float*)d_in[13];
  const float* bp1 = (const float*)d_in[14];
  const float* W2d = (const float*)d_in[15];
  const float* b2d = (const float*)d_in[16];
  float* ws  = (float*)d_ws;
  float* out = (float*)d_out;

  hipLaunchKernelGGL(gates_kernel, dim3(8), dim3(256), 0, stream,
                     words, w_masks, Wp0, bp0, Wp1, bp1, ws);
  hipLaunchKernelGGL(setup_kernel, dim3(1665), dim3(256), 0, stream,
                     v_map, v_mask, Wc0, Wc1, ws);
  hipLaunchKernelGGL(conv1_mfma, dim3(66, 8), dim3(256), 0, stream, bc0, ws);
  hipLaunchKernelGGL(conv2_mfma, dim3(16, 64), dim3(256), 0, stream,
                     bc1, W2d, b2d, v_mask, valid_num, ws, out);
  hipLaunchKernelGGL(mine_kernel, dim3(8), dim3(256), 0, stream, iou_maps, lam, ws);
  hipLaunchKernelGGL(loss_kernel, dim3(1), dim3(64), 0, stream, ws, out);
}

// Round 10
// 141.780 us; speedup vs baseline: 1.2492x; 1.0408x over previous
//
#include <hip/hip_runtime.h>
#include <hip/hip_bf16.h>
#include <math.h>

#define BB 8
#define CC 128
#define DD 64
#define TT 64
#define PP 4096
#define H1 66
#define LW 20
#define MARGINF 0.1f
#define NEG_SENTINEL -1.0e30f

// workspace layout (float offsets)
#define Y0_OFF   0            // y0w bf16 channel-last [8][66][66][128] = 2230272 f
#define VT_OFF   2230272      // vT bf16 [8][64][64][128] = 2097152 f
#define BP0_OFF  4327424      // Bpack(Wc0) 16x16 layout = 73728 f
#define NL_OFF   4401152      // per-sentence neg-loss [8] (old BP1 slot, unused gap)
#define W0_OFF   4479236      // weight0 [66][66] = 4356
#define W1_OFF   4483592      // weight1 [64][64] = 4096
#define G0_OFF   4487688      // [8][128]
#define G1_OFF   4488712      // [8][128]
#define S_OFF    4489736      // si [8][4096] = 32768 (diag maps only)
#define SCP_OFF  4522504      // packed scores u64 [64] = 128 f
#define BP1S_OFF 4522632      // 8x gate-scaled Bpack(Wc1*g0[i]) = 8*73728 f = 589824 f
// total ≈ 5112456 floats ≈ 20.5 MB

typedef __attribute__((ext_vector_type(8))) short bf16x8;
typedef __attribute__((ext_vector_type(4))) float f32x4;

// LDS (row,col) stride in shorts: 44 (=88B), conflict-light b128 access
#define ASTR 44

__device__ __forceinline__ unsigned f2bf(float f) {
  union { float f; unsigned u; } v; v.f = f;
  unsigned r = v.u + 0x7fffu + ((v.u >> 16) & 1u);   // RNE (setup only)
  return r >> 16;
}
__device__ __forceinline__ float bf2f(unsigned hw) {
  union { unsigned u; float f; } v; v.u = hw << 16;
  return v.f;
}
// native cast: compiler emits v_cvt_pk for pairs (m240)
__device__ __forceinline__ unsigned cvt_bf(float x) {
  __hip_bfloat16 h = __float2bfloat16(x);
  union { __hip_bfloat16 h; unsigned short u; } cv; cv.h = h;
  return (unsigned)cv.u;
}

// sign-select on 2 packed bf16: keep half iff sign(v) == wanted sign bit in W.
// relu(g*v)*Wc1 == select(v) * (Wc1*g), select(v) = g>0 ? max(v,0) : min(v,0)
__device__ __forceinline__ unsigned selbf(unsigned d, unsigned W) {
  unsigned diff = (d ^ W) & 0x80008000u;     // sign mismatch bits
  unsigned full = (diff >> 15) * 0xFFFFu;    // expand to half-word masks
  return d & ~full;                          // zero mismatched halves
}

// ---------------- gates: pooled words -> g0,g1 (must precede setup: B1 pack needs g0)
__global__ __launch_bounds__(256) void gates_kernel(
    const float* __restrict__ words, const float* __restrict__ w_masks,
    const float* __restrict__ Wp0, const float* __restrict__ bp0,
    const float* __restrict__ Wp1, const float* __restrict__ bp1,
    float* __restrict__ ws)
{
  __shared__ float smem[CC];
  int i = blockIdx.x;
  int t = threadIdx.x;
  if (t < CC) {
    float wsum = 0.f, acc = 0.f;
    for (int l = 0; l < LW; ++l) {
      float wm = w_masks[i * LW + l];
      wsum += wm;
      acc += words[(i * LW + l) * CC + t] * wm;
    }
    smem[t] = acc / fmaxf(wsum, 1.f);
  }
  __syncthreads();
  {
    int c = t & 127;
    const float* Wp = (t < 128) ? Wp0 : Wp1;
    const float* bp = (t < 128) ? bp0 : bp1;
    float a = bp[c];
    for (int k = 0; k < CC; ++k) a += smem[k] * Wp[k * CC + c];
    float g = tanhf(a);
    float* gout = ws + ((t < 128) ? G0_OFF : G1_OFF);
    gout[i * CC + c] = g;
  }
}

// ---------------- fused setup: pack B0, pack B1 x8 (one-read-eight-writes),
// transpose (XCD-aligned: vT[n] written on XCD n), w0/w1, scp zero
__global__ __launch_bounds__(256) void setup_kernel(
    const float* __restrict__ vmap, const float* __restrict__ v_mask,
    const float* __restrict__ Wc0, const float* __restrict__ Wc1,
    float* __restrict__ ws)
{
  __shared__ float smem[64 * 129];
  int bid = blockIdx.x;
  int t = threadIdx.x;

  if (bid < 576) {
    // B0 pack (unscaled)
    unsigned short* dst = (unsigned short*)(ws + BP0_OFF);
    int idx = bid * 256 + t;
    int j    = idx & 7;
    int lane = (idx >> 3) & 63;
    int cog  = (idx >> 9) & 7;
    int cic  = (idx >> 12) & 3;
    int kk   = idx >> 14;
    int co = cog * 16 + (lane & 15);
    int ci = cic * 32 + (lane >> 4) * 8 + j;
    dst[idx] = (unsigned short)f2bf(Wc0[(co * CC + ci) * 9 + kk]);
  } else if (bid < 1152) {
    // B1S pack: read each Wc1 element ONCE, write 8 gate-scaled copies
    for (int v = t; v < 8 * CC; v += 256) smem[v] = ws[G0_OFF + v];
    __syncthreads();
    int idx = (bid - 576) * 256 + t;
    int j    = idx & 7;
    int lane = (idx >> 3) & 63;
    int cog  = (idx >> 9) & 7;
    int cic  = (idx >> 12) & 3;
    int kk   = idx >> 14;
    int co = cog * 16 + (lane & 15);
    int ci = cic * 32 + (lane >> 4) * 8 + j;
    float wv = Wc1[(co * CC + ci) * 9 + kk];
    unsigned short* dst = (unsigned short*)(ws + BP1S_OFF);
#pragma unroll
    for (int si = 0; si < 8; ++si)
      dst[si * 147456 + idx] = (unsigned short)f2bf(wv * smem[si * CC + ci]);
  } else if (bid < 1664) {
    unsigned short* vT = (unsigned short*)(ws + VT_OFF);
    int b = bid - 1152;                  // 1152 % 8 == 0 -> XCD = b & 7
    int n = b & 7, y = b >> 3;           // XCD-aligned: vT[n] stays in XCD n's L2
    int x = t & 63, c4 = t >> 6;
    for (int rep = 0; rep < 32; ++rep) {
      int ci = rep * 4 + c4;
      smem[x * 129 + ci] = vmap[(((size_t)n * CC + ci) * DD + y) * TT + x];
    }
    __syncthreads();
    for (int rep = 0; rep < 16; ++rep) {
      int v = t + rep * 256;
      int xx = v >> 6, cip = v & 63;
      float a = smem[xx * 129 + cip * 2];
      float b2 = smem[xx * 129 + cip * 2 + 1];
      unsigned pk = f2bf(a) | (f2bf(b2) << 16);
      *(unsigned*)&vT[(((size_t)(n * DD + y) * TT + xx)) * CC + cip * 2] = pk;
    }
  } else {
    if (t < 128) ((unsigned*)(ws + SCP_OFF))[t] = 0u;   // zero packed scores
    float* w0 = ws + W0_OFF;
    float* w1 = ws + W1_OFF;
    for (int idx = t; idx < H1 * H1; idx += 256) {
      int y = idx / H1, x = idx % H1;
      float cnt = 0.f;
      for (int ky = 0; ky < 3; ++ky)
        for (int kx = 0; kx < 3; ++kx) {
          int iy = y + ky - 2, ix = x + kx - 2;
          if (iy >= 0 && iy < DD && ix >= 0 && ix < TT) cnt += v_mask[iy * TT + ix];
        }
      w0[idx] = (cnt > 0.f) ? 1.f / fmaxf(cnt, 1.f) : 0.f;
    }
    __syncthreads();
    for (int idx = t; idx < DD * TT; idx += 256) {
      int y = idx / TT, x = idx % TT;
      float cnt = 0.f;
      for (int ky = 0; ky < 3; ++ky)
        for (int kx = 0; kx < 3; ++kx)
          cnt += (w0[(y + ky) * H1 + (x + kx)] > 0.f) ? 1.f : 0.f;
      w1[idx] = (cnt > 0.f) ? 1.f / fmaxf(cnt, 1.f) : 0.f;
    }
  }
}

// conv1: XCD-aligned n = id&7 (kept from R25: helped ~4us)
__global__ __launch_bounds__(256, 2) void conv1_mfma(
    const float* __restrict__ bc0, float* __restrict__ ws)
{
  const unsigned short* vT = (const unsigned short*)(ws + VT_OFF);
  const unsigned short* Bp = (const unsigned short*)(ws + BP0_OFF);
  const float* w0arr = ws + W0_OFF;
  unsigned short* y0w = (unsigned short*)(ws + Y0_OFF);

  __shared__ unsigned short Alds[3 * 68 * ASTR];   // 17952 B

  int t = threadIdx.x;
  int id = blockIdx.x + 66 * blockIdx.y;   // 0..527
  int n  = id & 7;                         // XCD-aligned
  int r0 = id >> 3;                        // output row 0..65
  int lane = t & 63, w = t >> 6;           // w = co quarter
  int l15 = lane & 15, l4 = lane >> 4;
  int co0 = w * 32;

  f32x4 acc[5][2];
#pragma unroll
  for (int mf = 0; mf < 5; ++mf)
#pragma unroll
    for (int nf = 0; nf < 2; ++nf) acc[mf][nf] = (f32x4){0.f, 0.f, 0.f, 0.f};

  for (int cic = 0; cic < 4; ++cic) {
    __syncthreads();
    for (int u = t; u < 816; u += 256) {
      int cig = u & 3, rest = u >> 2;
      int col = rest % 68, r = rest / 68;
      int iy = r0 - 2 + r, ix = col - 2;
      uint4 val = {0u, 0u, 0u, 0u};
      if (iy >= 0 && iy < DD && ix >= 0 && ix < TT)
        val = *(const uint4*)&vT[(((size_t)(n * DD + iy) * TT + ix)) * CC + cic * 32 + cig * 8];
      *(uint4*)&Alds[(r * 68 + col) * ASTR + cig * 8] = val;
    }
    __syncthreads();
    __builtin_amdgcn_s_setprio(1);
#pragma unroll
    for (int kk = 0; kk < 9; ++kk) {
      int ky = kk / 3, kx = kk % 3;
      bf16x8 af[5], bfr[2];
#pragma unroll
      for (int mf = 0; mf < 5; ++mf) {
        int c = mf * 16 + l15;
        int cc = c > 65 ? 65 : c;
        af[mf] = *(const bf16x8*)&Alds[(ky * 68 + cc + kx) * ASTR + l4 * 8];
      }
#pragma unroll
      for (int nf = 0; nf < 2; ++nf)
        bfr[nf] = *(const bf16x8*)&Bp[(((kk * 4 + cic) * 8 + w * 2 + nf) * 64 + lane) * 8];
#pragma unroll
      for (int mf = 0; mf < 5; ++mf)
#pragma unroll
        for (int nf = 0; nf < 2; ++nf)
          acc[mf][nf] = __builtin_amdgcn_mfma_f32_16x16x32_bf16(af[mf], bfr[nf], acc[mf][nf], 0, 0, 0);
    }
    __builtin_amdgcn_s_setprio(0);
  }

  int y = r0;
#pragma unroll
  for (int nf = 0; nf < 2; ++nf) {
    int co = co0 + nf * 16 + l15;
    float bcv = bc0[co];
#pragma unroll
    for (int mf = 0; mf < 5; ++mf)
#pragma unroll
      for (int rg = 0; rg < 4; ++rg) {
        int c = mf * 16 + l4 * 4 + rg;
        if (c < H1) {
          float v = (acc[mf][nf][rg] + bcv) * w0arr[y * H1 + c];
          y0w[((size_t)(n * H1 + y) * H1 + c) * CC + co] = (unsigned short)cvt_bf(v);
        }
      }
  }
}

// conv2 R26: 2-row tiles for 3 blocks/CU occupancy.
// acc[8][4] (128 AGPR) + 128 VGPR = 256 regs pinned occupancy at 2 blocks/CU;
// every overlap attempt failed on that wall. This halves the tile: acc[4][4]
// (64 AGPR), wave = 1 row x 64 col x 64 co, launch_bounds(256,3) caps 170
// regs/wave -> 3 blocks/CU. Staging +33% (4-row halo for 2 rows) but hidden
// under 2 other blocks' MFMA. Staging loop + selbf + global-B MFMA cluster
// unchanged in form (proven). i = by&7, n = by>>3 (R22 proven mapping).
__global__ __launch_bounds__(256, 3) void conv2_mfma(
    const float* __restrict__ bc1, const float* __restrict__ W2d,
    const float* __restrict__ b2d, const float* __restrict__ v_mask,
    const int* __restrict__ valid_num, float* __restrict__ ws,
    float* __restrict__ out)
{
  const unsigned short* y0w = (const unsigned short*)(ws + Y0_OFF);
  const float* w1m = ws + W1_OFF;
  const float* g0 = ws + G0_OFF;
  const float* g1 = ws + G1_OFF;
  unsigned long long* scp = (unsigned long long*)(ws + SCP_OFF);

  __shared__ unsigned short Alds[4 * 66 * ASTR];   // 23232 B
  __shared__ unsigned msk[16][4];                  // sign masks per (cic,cig)
  __shared__ float redl[2][2][64];
  __shared__ unsigned long long kred[2];

  int t = threadIdx.x;
  int r0 = blockIdx.x;                        // output rows r0*2, r0*2+1 (r0 in 0..31)
  int i = blockIdx.y & 7, n = blockIdx.y >> 3;   // n-major: L2 locality on y0w[n]
  int lane = t & 63, w = t >> 6;
  int wr = w >> 1, wc = w & 1;                // wr = row, wc = co half
  int l15 = lane & 15, l4 = lane >> 4;

  const unsigned short* Bp = (const unsigned short*)(ws + BP1S_OFF) + (size_t)i * 147456;

  if (t < 16) {                               // t = cic*4+cig -> channels t*8..t*8+7
    int ch = t * 8;
    msk[t][0] = (g0[i * CC + ch + 0] > 0.f ? 0u : 0x8000u) | (g0[i * CC + ch + 1] > 0.f ? 0u : 0x80000000u);
    msk[t][1] = (g0[i * CC + ch + 2] > 0.f ? 0u : 0x8000u) | (g0[i * CC + ch + 3] > 0.f ? 0u : 0x80000000u);
    msk[t][2] = (g0[i * CC + ch + 4] > 0.f ? 0u : 0x8000u) | (g0[i * CC + ch + 5] > 0.f ? 0u : 0x80000000u);
    msk[t][3] = (g0[i * CC + ch + 6] > 0.f ? 0u : 0x8000u) | (g0[i * CC + ch + 7] > 0.f ? 0u : 0x80000000u);
  }

  f32x4 acc[4][4];
#pragma unroll
  for (int mf = 0; mf < 4; ++mf)
#pragma unroll
    for (int nf = 0; nf < 4; ++nf) acc[mf][nf] = (f32x4){0.f, 0.f, 0.f, 0.f};

  for (int cic = 0; cic < 4; ++cic) {
    __syncthreads();
    // stage 4 rows x 66 cols x 32ci: 1056 uint4s; select applied via sign bits
    {
      uint4 mv = *(const uint4*)&msk[(cic << 2) | (t & 3)][0];
      for (int u = t; u < 1056; u += 256) {
        int cig = u & 3, cr = u >> 2;
        int col = cr % 66, row = cr / 66;       // row 0..3
        const unsigned short* src = y0w
            + ((size_t)((n * H1 + r0 * 2 + row) * H1 + col)) * CC + cic * 32 + cig * 8;
        uint4 raw = *(const uint4*)src;
        uint4 pk;
        pk.x = selbf(raw.x, mv.x);
        pk.y = selbf(raw.y, mv.y);
        pk.z = selbf(raw.z, mv.z);
        pk.w = selbf(raw.w, mv.w);
        *(uint4*)&Alds[(row * 66 + col) * ASTR + cig * 8] = pk;
      }
    }
    __syncthreads();
    __builtin_amdgcn_s_setprio(1);
#pragma unroll
    for (int kk = 0; kk < 9; ++kk) {
      int ky = kk / 3, kx = kk % 3;
      bf16x8 af[4], bfr[4];
#pragma unroll
      for (int mf = 0; mf < 4; ++mf) {
        int row = wr + ky;                          // 0..3
        int col = mf * 16 + l15 + kx;               // 0..65
        af[mf] = *(const bf16x8*)&Alds[(row * 66 + col) * ASTR + l4 * 8];
      }
#pragma unroll
      for (int nf = 0; nf < 4; ++nf)
        bfr[nf] = *(const bf16x8*)&Bp[(((kk * 4 + cic) * 8 + wc * 4 + nf) * 64 + lane) * 8];
#pragma unroll
      for (int mf = 0; mf < 4; ++mf)
#pragma unroll
        for (int nf = 0; nf < 4; ++nf)
          acc[mf][nf] = __builtin_amdgcn_mfma_f32_16x16x32_bf16(af[mf], bfr[nf], acc[mf][nf], 0, 0, 0);
    }
    __builtin_amdgcn_s_setprio(0);
  }

  // epilogue: relu((acc+bc1)*g1)*W2d, reduce over co; weight1 factored out (w1>=0)
  float part[4][4];
#pragma unroll
  for (int mf = 0; mf < 4; ++mf)
#pragma unroll
    for (int rg = 0; rg < 4; ++rg) part[mf][rg] = 0.f;
#pragma unroll
  for (int nf = 0; nf < 4; ++nf) {
    int co = wc * 64 + nf * 16 + l15;
    float bcv = bc1[co];
    float gv = g1[i * CC + co];
    float wv = W2d[co];
#pragma unroll
    for (int mf = 0; mf < 4; ++mf)
#pragma unroll
      for (int rg = 0; rg < 4; ++rg) {
        float z = (acc[mf][nf][rg] + bcv) * gv;
        part[mf][rg] += fmaxf(z, 0.f) * wv;
      }
  }
#pragma unroll
  for (int mask = 1; mask < 16; mask <<= 1)
#pragma unroll
    for (int mf = 0; mf < 4; ++mf)
#pragma unroll
      for (int rg = 0; rg < 4; ++rg)
        part[mf][rg] += __shfl_xor(part[mf][rg], mask, 64);
  if (l15 == 0) {
#pragma unroll
    for (int mf = 0; mf < 4; ++mf)
#pragma unroll
      for (int rg = 0; rg < 4; ++rg)
        redl[wc][wr][mf * 16 + l4 * 4 + rg] = part[mf][rg];
  }
  __syncthreads();
  if (t < 128) {
    int row = t >> 6, col = t & 63;             // row 0..1
    int rowg = r0 * 2 + row;
    float v = redl[0][row][col] + redl[1][row][col];
    float logit = w1m[rowg * TT + col] * v + b2d[0];
    float sig = 1.f / (1.f + expf(-logit));
    bool m = (v_mask[rowg * TT + col] > 0.f) && (col < valid_num[n]);
    int p = rowg * TT + col;
    if (i == n) {
      ws[S_OFF + i * PP + p] = m ? sig : -INFINITY;           // for hard-neg mining
      out[1 + i * PP + p] = m ? sig : NEG_SENTINEL;           // positive_map output
    }
    unsigned long long key = 0ull;
    if (m) key = ((unsigned long long)__float_as_uint(sig) << 32)
                 | (unsigned long long)(0xFFFFFFFFu - (unsigned)p);
#pragma unroll
    for (int mk = 1; mk < 64; mk <<= 1) {
      unsigned lo = __shfl_xor((unsigned)key, mk, 64);
      unsigned hi = __shfl_xor((unsigned)(key >> 32), mk, 64);
      unsigned long long o = ((unsigned long long)hi << 32) | lo;
      if (o > key) key = o;
    }
    if (lane == 0) kred[w] = key;
  }
  __syncthreads();
  if (t == 0) {
    unsigned long long k = kred[0];
    if (kred[1] > k) k = kred[1];
    if (k) atomicMax(&scp[i * 8 + n], k);
  }
}

// hard-negative mining: one block per sentence (8 blocks x 256 thr)
__global__ __launch_bounds__(256) void mine_kernel(
    const float* __restrict__ iou_maps, const float* __restrict__ lam,
    float* __restrict__ ws)
{
  __shared__ float wred[4];
  int i = blockIdx.x;
  int t = threadIdx.x, lane = t & 63, w = t >> 6;
  const unsigned long long* scp = (const unsigned long long*)(ws + SCP_OFF);

  unsigned long long dk = scp[i * 9];                  // diag (i,i)
  float diag_sc = __uint_as_float((unsigned)(dk >> 32));
  int pidx = (int)(0xFFFFFFFFu - (unsigned)(dk & 0xFFFFFFFFu));
  float lamv = lam[0];
  const float* row = iou_maps + (size_t)pidx * PP;
  const float* si = ws + S_OFF + (size_t)i * PP;
  float hv = -INFINITY;
  for (int p = t; p < PP; p += 256) {
    float v = si[p];
    if (row[p] < lamv && isfinite(v)) hv = fmaxf(hv, v);
  }
#pragma unroll
  for (int m = 1; m < 64; m <<= 1) hv = fmaxf(hv, __shfl_xor(hv, m, 64));
  if (lane == 0) wred[w] = hv;
  __syncthreads();
  if (t == 0) {
    float h = fmaxf(fmaxf(wred[0], wred[1]), fmaxf(wred[2], wred[3]));
    ws[NL_OFF + i] = fmaxf(0.f, MARGINF + h - diag_sc);
  }
}

// final loss: 1 wave, sorting-network top-3 (unchanged math)
__global__ __launch_bounds__(64) void loss_kernel(
    float* __restrict__ ws, float* __restrict__ out)
{
  __shared__ float scsh[64];
  int lane = threadIdx.x;
  const unsigned long long* scp = (const unsigned long long*)(ws + SCP_OFF);
  scsh[lane] = __uint_as_float((unsigned)(scp[lane] >> 32));
  __syncthreads();

  float partial = 0.f;
  if (lane < 16) {
    int r = lane & 7;
    bool im = lane >= 8;
    float diag = scsh[r * 8 + r];
    float v[8];
#pragma unroll
    for (int j = 0; j < 8; ++j) {
      float scv = im ? scsh[j * 8 + r] : scsh[r * 8 + j];
      float h = fmaxf(0.f, MARGINF + scv - diag);
      v[j] = (j == r) ? 0.f : h;
    }
#define CE(a, b) { float mx = fmaxf(v[a], v[b]); float mn = fminf(v[a], v[b]); v[a] = mx; v[b] = mn; }
    CE(0,1) CE(2,3) CE(4,5) CE(6,7)
    CE(0,2) CE(1,3) CE(4,6) CE(5,7)
    CE(1,2) CE(5,6)
    CE(0,4) CE(1,5) CE(2,6) CE(3,7)
    CE(2,4) CE(3,5)
    CE(1,2) CE(3,4) CE(5,6)
#undef CE
    partial = v[0] + v[1] + v[2];
  } else if (lane >= 16 && lane < 24) {
    partial = ws[NL_OFF + lane - 16];
  }
#pragma unroll
  for (int m = 1; m < 64; m <<= 1) partial += __shfl_xor(partial, m, 64);
  if (lane == 0) out[0] = partial * 0.125f;
}

extern "C" void kernel_launch(void* const* d_in, const int* in_sizes, int n_in,
                              void* d_out, int out_size, void* d_ws, size_t ws_size,
                              hipStream_t stream)
{
  const float* v_map     = (const float*)d_in[0];
  const float* words     = (const float*)d_in[1];
  const float* w_masks   = (const float*)d_in[2];
  const float* v_mask    = (const float*)d_in[3];
  const int*   valid_num = (const int*)d_in[4];
  const float* iou_maps  = (const float*)d_in[5];
  const float* lam       = (const float*)d_in[6];
  const float* Wc0 = (const float*)d_in[7];
  const float* bc0 = (const float*)d_in[8];
  const float* Wc1 = (const float*)d_in[9];
  const float* bc1 = (const float*)d_in[10];
  const float* Wp0 = (const float*)d_in[11];
  const float* bp0 = (const float*)d_in[12];
  const float* Wp1 = (const float*)d_in[13];
  const float* bp1 = (const float*)d_in[14];
  const float* W2d = (const float*)d_in[15];
  const float* b2d = (const float*)d_in[16];
  float* ws  = (float*)d_ws;
  float* out = (float*)d_out;

  hipLaunchKernelGGL(gates_kernel, dim3(8), dim3(256), 0, stream,
                     words, w_masks, Wp0, bp0, Wp1, bp1, ws);
  hipLaunchKernelGGL(setup_kernel, dim3(1665), dim3(256), 0, stream,
                     v_map, v_mask, Wc0, Wc1, ws);
  hipLaunchKernelGGL(conv1_mfma, dim3(66, 8), dim3(256), 0, stream, bc0, ws);
  hipLaunchKernelGGL(conv2_mfma, dim3(32, 64), dim3(256), 0, stream,
                     bc1, W2d, b2d, v_mask, valid_num, ws, out);
  hipLaunchKernelGGL(mine_kernel, dim3(8), dim3(256), 0, stream, iou_maps, lam, ws);
  hipLaunchKernelGGL(loss_kernel, dim3(1), dim3(64), 0, stream, ws, out);
}

// Round 11
// 141.287 us; speedup vs baseline: 1.2535x; 1.0035x over previous
//
#include <hip/hip_runtime.h>
#include <hip/hip_bf16.h>
#include <math.h>

#define BB 8
#define CC 128
#define DD 64
#define TT 64
#define PP 4096
#define H1 66
#define LW 20
#define MARGINF 0.1f
#define NEG_SENTINEL -1.0e30f

// workspace layout (float offsets)
#define Y0_OFF   0            // y0w bf16 channel-last [8][66][66][128] = 2230272 f
#define VT_OFF   2230272      // vT bf16 [8][64][64][128] = 2097152 f
#define BP0_OFF  4327424      // Bpack(Wc0) 16x16 layout = 73728 f
#define NL_OFF   4401152      // per-sentence neg-loss [8] (old BP1 slot, unused gap)
#define W0_OFF   4479236      // weight0 [66][66] = 4356
#define W1_OFF   4483592      // weight1 [64][64] = 4096
#define G0_OFF   4487688      // [8][128]
#define G1_OFF   4488712      // [8][128]
#define S_OFF    4489736      // si [8][4096] = 32768 (diag maps only)
#define SCP_OFF  4522504      // packed scores u64 [64] = 128 f
#define BP1S_OFF 4522632      // 8x gate-scaled Bpack(Wc1*g0[i]) = 8*73728 f = 589824 f
// total ≈ 5112456 floats ≈ 20.5 MB

typedef __attribute__((ext_vector_type(8))) short bf16x8;
typedef __attribute__((ext_vector_type(4))) float f32x4;

// LDS (row,col) stride in shorts: 44 (=88B), conflict-light b128 access
#define ASTR 44

__device__ __forceinline__ unsigned f2bf(float f) {
  union { float f; unsigned u; } v; v.f = f;
  unsigned r = v.u + 0x7fffu + ((v.u >> 16) & 1u);   // RNE (setup only)
  return r >> 16;
}
__device__ __forceinline__ float bf2f(unsigned hw) {
  union { unsigned u; float f; } v; v.u = hw << 16;
  return v.f;
}
// native cast: compiler emits v_cvt_pk for pairs (m240)
__device__ __forceinline__ unsigned cvt_bf(float x) {
  __hip_bfloat16 h = __float2bfloat16(x);
  union { __hip_bfloat16 h; unsigned short u; } cv; cv.h = h;
  return (unsigned)cv.u;
}

// sign-select on 2 packed bf16: keep half iff sign(v) == wanted sign bit in W.
// relu(g*v)*Wc1 == select(v) * (Wc1*g), select(v) = g>0 ? max(v,0) : min(v,0)
__device__ __forceinline__ unsigned selbf(unsigned d, unsigned W) {
  unsigned diff = (d ^ W) & 0x80008000u;     // sign mismatch bits
  unsigned full = (diff >> 15) * 0xFFFFu;    // expand to half-word masks
  return d & ~full;                          // zero mismatched halves
}

// ---------------- gates: pooled words -> g0,g1 (must precede setup: B1 pack needs g0)
__global__ __launch_bounds__(256) void gates_kernel(
    const float* __restrict__ words, const float* __restrict__ w_masks,
    const float* __restrict__ Wp0, const float* __restrict__ bp0,
    const float* __restrict__ Wp1, const float* __restrict__ bp1,
    float* __restrict__ ws)
{
  __shared__ float smem[CC];
  int i = blockIdx.x;
  int t = threadIdx.x;
  if (t < CC) {
    float wsum = 0.f, acc = 0.f;
    for (int l = 0; l < LW; ++l) {
      float wm = w_masks[i * LW + l];
      wsum += wm;
      acc += words[(i * LW + l) * CC + t] * wm;
    }
    smem[t] = acc / fmaxf(wsum, 1.f);
  }
  __syncthreads();
  {
    int c = t & 127;
    const float* Wp = (t < 128) ? Wp0 : Wp1;
    const float* bp = (t < 128) ? bp0 : bp1;
    float a = bp[c];
    for (int k = 0; k < CC; ++k) a += smem[k] * Wp[k * CC + c];
    float g = tanhf(a);
    float* gout = ws + ((t < 128) ? G0_OFF : G1_OFF);
    gout[i * CC + c] = g;
  }
}

// ---------------- fused setup: pack B0, pack B1 x8 (one-read-eight-writes),
// transpose (XCD-aligned: vT[n] written on XCD n), w0/w1, scp zero
__global__ __launch_bounds__(256) void setup_kernel(
    const float* __restrict__ vmap, const float* __restrict__ v_mask,
    const float* __restrict__ Wc0, const float* __restrict__ Wc1,
    float* __restrict__ ws)
{
  __shared__ float smem[64 * 129];
  int bid = blockIdx.x;
  int t = threadIdx.x;

  if (bid < 576) {
    // B0 pack (unscaled)
    unsigned short* dst = (unsigned short*)(ws + BP0_OFF);
    int idx = bid * 256 + t;
    int j    = idx & 7;
    int lane = (idx >> 3) & 63;
    int cog  = (idx >> 9) & 7;
    int cic  = (idx >> 12) & 3;
    int kk   = idx >> 14;
    int co = cog * 16 + (lane & 15);
    int ci = cic * 32 + (lane >> 4) * 8 + j;
    dst[idx] = (unsigned short)f2bf(Wc0[(co * CC + ci) * 9 + kk]);
  } else if (bid < 1152) {
    // B1S pack: read each Wc1 element ONCE, write 8 gate-scaled copies
    for (int v = t; v < 8 * CC; v += 256) smem[v] = ws[G0_OFF + v];
    __syncthreads();
    int idx = (bid - 576) * 256 + t;
    int j    = idx & 7;
    int lane = (idx >> 3) & 63;
    int cog  = (idx >> 9) & 7;
    int cic  = (idx >> 12) & 3;
    int kk   = idx >> 14;
    int co = cog * 16 + (lane & 15);
    int ci = cic * 32 + (lane >> 4) * 8 + j;
    float wv = Wc1[(co * CC + ci) * 9 + kk];
    unsigned short* dst = (unsigned short*)(ws + BP1S_OFF);
#pragma unroll
    for (int si = 0; si < 8; ++si)
      dst[si * 147456 + idx] = (unsigned short)f2bf(wv * smem[si * CC + ci]);
  } else if (bid < 1664) {
    unsigned short* vT = (unsigned short*)(ws + VT_OFF);
    int b = bid - 1152;                  // 1152 % 8 == 0 -> XCD = b & 7
    int n = b & 7, y = b >> 3;           // XCD-aligned: vT[n] stays in XCD n's L2
    int x = t & 63, c4 = t >> 6;
    for (int rep = 0; rep < 32; ++rep) {
      int ci = rep * 4 + c4;
      smem[x * 129 + ci] = vmap[(((size_t)n * CC + ci) * DD + y) * TT + x];
    }
    __syncthreads();
    for (int rep = 0; rep < 16; ++rep) {
      int v = t + rep * 256;
      int xx = v >> 6, cip = v & 63;
      float a = smem[xx * 129 + cip * 2];
      float b2 = smem[xx * 129 + cip * 2 + 1];
      unsigned pk = f2bf(a) | (f2bf(b2) << 16);
      *(unsigned*)&vT[(((size_t)(n * DD + y) * TT + xx)) * CC + cip * 2] = pk;
    }
  } else {
    if (t < 128) ((unsigned*)(ws + SCP_OFF))[t] = 0u;   // zero packed scores
    float* w0 = ws + W0_OFF;
    float* w1 = ws + W1_OFF;
    for (int idx = t; idx < H1 * H1; idx += 256) {
      int y = idx / H1, x = idx % H1;
      float cnt = 0.f;
      for (int ky = 0; ky < 3; ++ky)
        for (int kx = 0; kx < 3; ++kx) {
          int iy = y + ky - 2, ix = x + kx - 2;
          if (iy >= 0 && iy < DD && ix >= 0 && ix < TT) cnt += v_mask[iy * TT + ix];
        }
      w0[idx] = (cnt > 0.f) ? 1.f / fmaxf(cnt, 1.f) : 0.f;
    }
    __syncthreads();
    for (int idx = t; idx < DD * TT; idx += 256) {
      int y = idx / TT, x = idx % TT;
      float cnt = 0.f;
      for (int ky = 0; ky < 3; ++ky)
        for (int kx = 0; kx < 3; ++kx)
          cnt += (w0[(y + ky) * H1 + (x + kx)] > 0.f) ? 1.f : 0.f;
      w1[idx] = (cnt > 0.f) ? 1.f / fmaxf(cnt, 1.f) : 0.f;
    }
  }
}

// conv1: XCD-aligned n = id&7 (kept from R25: helped ~4us)
__global__ __launch_bounds__(256, 2) void conv1_mfma(
    const float* __restrict__ bc0, float* __restrict__ ws)
{
  const unsigned short* vT = (const unsigned short*)(ws + VT_OFF);
  const unsigned short* Bp = (const unsigned short*)(ws + BP0_OFF);
  const float* w0arr = ws + W0_OFF;
  unsigned short* y0w = (unsigned short*)(ws + Y0_OFF);

  __shared__ unsigned short Alds[3 * 68 * ASTR];   // 17952 B

  int t = threadIdx.x;
  int id = blockIdx.x + 66 * blockIdx.y;   // 0..527
  int n  = id & 7;                         // XCD-aligned
  int r0 = id >> 3;                        // output row 0..65
  int lane = t & 63, w = t >> 6;           // w = co quarter
  int l15 = lane & 15, l4 = lane >> 4;
  int co0 = w * 32;

  f32x4 acc[5][2];
#pragma unroll
  for (int mf = 0; mf < 5; ++mf)
#pragma unroll
    for (int nf = 0; nf < 2; ++nf) acc[mf][nf] = (f32x4){0.f, 0.f, 0.f, 0.f};

  for (int cic = 0; cic < 4; ++cic) {
    __syncthreads();
    for (int u = t; u < 816; u += 256) {
      int cig = u & 3, rest = u >> 2;
      int col = rest % 68, r = rest / 68;
      int iy = r0 - 2 + r, ix = col - 2;
      uint4 val = {0u, 0u, 0u, 0u};
      if (iy >= 0 && iy < DD && ix >= 0 && ix < TT)
        val = *(const uint4*)&vT[(((size_t)(n * DD + iy) * TT + ix)) * CC + cic * 32 + cig * 8];
      *(uint4*)&Alds[(r * 68 + col) * ASTR + cig * 8] = val;
    }
    __syncthreads();
    __builtin_amdgcn_s_setprio(1);
#pragma unroll
    for (int kk = 0; kk < 9; ++kk) {
      int ky = kk / 3, kx = kk % 3;
      bf16x8 af[5], bfr[2];
#pragma unroll
      for (int mf = 0; mf < 5; ++mf) {
        int c = mf * 16 + l15;
        int cc = c > 65 ? 65 : c;
        af[mf] = *(const bf16x8*)&Alds[(ky * 68 + cc + kx) * ASTR + l4 * 8];
      }
#pragma unroll
      for (int nf = 0; nf < 2; ++nf)
        bfr[nf] = *(const bf16x8*)&Bp[(((kk * 4 + cic) * 8 + w * 2 + nf) * 64 + lane) * 8];
#pragma unroll
      for (int mf = 0; mf < 5; ++mf)
#pragma unroll
        for (int nf = 0; nf < 2; ++nf)
          acc[mf][nf] = __builtin_amdgcn_mfma_f32_16x16x32_bf16(af[mf], bfr[nf], acc[mf][nf], 0, 0, 0);
    }
    __builtin_amdgcn_s_setprio(0);
  }

  int y = r0;
#pragma unroll
  for (int nf = 0; nf < 2; ++nf) {
    int co = co0 + nf * 16 + l15;
    float bcv = bc0[co];
#pragma unroll
    for (int mf = 0; mf < 5; ++mf)
#pragma unroll
      for (int rg = 0; rg < 4; ++rg) {
        int c = mf * 16 + l4 * 4 + rg;
        if (c < H1) {
          float v = (acc[mf][nf][rg] + bcv) * w0arr[y * H1 + c];
          y0w[((size_t)(n * H1 + y) * H1 + c) * CC + co] = (unsigned short)cvt_bf(v);
        }
      }
  }
}

// conv2 R27: identical to R26 (2-row tiles, proven 81.4us) with ONE change:
// __launch_bounds__(256,4). R26 measured 64 VGPR + 64 AGPR = 128 regs/wave,
// which supports 4 waves/SIMD (pool halves at 64/128/256); LDS 24.6KB x 4 =
// 98KB also fits. The (256,3) bound itself was the only thing pinning
// occupancy at 3 blocks/CU. 4th resident block -> staging hides under 3
// blocks' MFMA. Tripwires: occupancy stuck at 40 or WRITE_SIZE in MBs.
__global__ __launch_bounds__(256, 4) void conv2_mfma(
    const float* __restrict__ bc1, const float* __restrict__ W2d,
    const float* __restrict__ b2d, const float* __restrict__ v_mask,
    const int* __restrict__ valid_num, float* __restrict__ ws,
    float* __restrict__ out)
{
  const unsigned short* y0w = (const unsigned short*)(ws + Y0_OFF);
  const float* w1m = ws + W1_OFF;
  const float* g0 = ws + G0_OFF;
  const float* g1 = ws + G1_OFF;
  unsigned long long* scp = (unsigned long long*)(ws + SCP_OFF);

  __shared__ unsigned short Alds[4 * 66 * ASTR];   // 23232 B
  __shared__ unsigned msk[16][4];                  // sign masks per (cic,cig)
  __shared__ float redl[2][2][64];
  __shared__ unsigned long long kred[2];

  int t = threadIdx.x;
  int r0 = blockIdx.x;                        // output rows r0*2, r0*2+1 (r0 in 0..31)
  int i = blockIdx.y & 7, n = blockIdx.y >> 3;   // n-major: L2 locality on y0w[n]
  int lane = t & 63, w = t >> 6;
  int wr = w >> 1, wc = w & 1;                // wr = row, wc = co half
  int l15 = lane & 15, l4 = lane >> 4;

  const unsigned short* Bp = (const unsigned short*)(ws + BP1S_OFF) + (size_t)i * 147456;

  if (t < 16) {                               // t = cic*4+cig -> channels t*8..t*8+7
    int ch = t * 8;
    msk[t][0] = (g0[i * CC + ch + 0] > 0.f ? 0u : 0x8000u) | (g0[i * CC + ch + 1] > 0.f ? 0u : 0x80000000u);
    msk[t][1] = (g0[i * CC + ch + 2] > 0.f ? 0u : 0x8000u) | (g0[i * CC + ch + 3] > 0.f ? 0u : 0x80000000u);
    msk[t][2] = (g0[i * CC + ch + 4] > 0.f ? 0u : 0x8000u) | (g0[i * CC + ch + 5] > 0.f ? 0u : 0x80000000u);
    msk[t][3] = (g0[i * CC + ch + 6] > 0.f ? 0u : 0x8000u) | (g0[i * CC + ch + 7] > 0.f ? 0u : 0x80000000u);
  }

  f32x4 acc[4][4];
#pragma unroll
  for (int mf = 0; mf < 4; ++mf)
#pragma unroll
    for (int nf = 0; nf < 4; ++nf) acc[mf][nf] = (f32x4){0.f, 0.f, 0.f, 0.f};

  for (int cic = 0; cic < 4; ++cic) {
    __syncthreads();
    // stage 4 rows x 66 cols x 32ci: 1056 uint4s; select applied via sign bits
    {
      uint4 mv = *(const uint4*)&msk[(cic << 2) | (t & 3)][0];
      for (int u = t; u < 1056; u += 256) {
        int cig = u & 3, cr = u >> 2;
        int col = cr % 66, row = cr / 66;       // row 0..3
        const unsigned short* src = y0w
            + ((size_t)((n * H1 + r0 * 2 + row) * H1 + col)) * CC + cic * 32 + cig * 8;
        uint4 raw = *(const uint4*)src;
        uint4 pk;
        pk.x = selbf(raw.x, mv.x);
        pk.y = selbf(raw.y, mv.y);
        pk.z = selbf(raw.z, mv.z);
        pk.w = selbf(raw.w, mv.w);
        *(uint4*)&Alds[(row * 66 + col) * ASTR + cig * 8] = pk;
      }
    }
    __syncthreads();
    __builtin_amdgcn_s_setprio(1);
#pragma unroll
    for (int kk = 0; kk < 9; ++kk) {
      int ky = kk / 3, kx = kk % 3;
      bf16x8 af[4], bfr[4];
#pragma unroll
      for (int mf = 0; mf < 4; ++mf) {
        int row = wr + ky;                          // 0..3
        int col = mf * 16 + l15 + kx;               // 0..65
        af[mf] = *(const bf16x8*)&Alds[(row * 66 + col) * ASTR + l4 * 8];
      }
#pragma unroll
      for (int nf = 0; nf < 4; ++nf)
        bfr[nf] = *(const bf16x8*)&Bp[(((kk * 4 + cic) * 8 + wc * 4 + nf) * 64 + lane) * 8];
#pragma unroll
      for (int mf = 0; mf < 4; ++mf)
#pragma unroll
        for (int nf = 0; nf < 4; ++nf)
          acc[mf][nf] = __builtin_amdgcn_mfma_f32_16x16x32_bf16(af[mf], bfr[nf], acc[mf][nf], 0, 0, 0);
    }
    __builtin_amdgcn_s_setprio(0);
  }

  // epilogue: relu((acc+bc1)*g1)*W2d, reduce over co; weight1 factored out (w1>=0)
  float part[4][4];
#pragma unroll
  for (int mf = 0; mf < 4; ++mf)
#pragma unroll
    for (int rg = 0; rg < 4; ++rg) part[mf][rg] = 0.f;
#pragma unroll
  for (int nf = 0; nf < 4; ++nf) {
    int co = wc * 64 + nf * 16 + l15;
    float bcv = bc1[co];
    float gv = g1[i * CC + co];
    float wv = W2d[co];
#pragma unroll
    for (int mf = 0; mf < 4; ++mf)
#pragma unroll
      for (int rg = 0; rg < 4; ++rg) {
        float z = (acc[mf][nf][rg] + bcv) * gv;
        part[mf][rg] += fmaxf(z, 0.f) * wv;
      }
  }
#pragma unroll
  for (int mask = 1; mask < 16; mask <<= 1)
#pragma unroll
    for (int mf = 0; mf < 4; ++mf)
#pragma unroll
      for (int rg = 0; rg < 4; ++rg)
        part[mf][rg] += __shfl_xor(part[mf][rg], mask, 64);
  if (l15 == 0) {
#pragma unroll
    for (int mf = 0; mf < 4; ++mf)
#pragma unroll
      for (int rg = 0; rg < 4; ++rg)
        redl[wc][wr][mf * 16 + l4 * 4 + rg] = part[mf][rg];
  }
  __syncthreads();
  if (t < 128) {
    int row = t >> 6, col = t & 63;             // row 0..1
    int rowg = r0 * 2 + row;
    float v = redl[0][row][col] + redl[1][row][col];
    float logit = w1m[rowg * TT + col] * v + b2d[0];
    float sig = 1.f / (1.f + expf(-logit));
    bool m = (v_mask[rowg * TT + col] > 0.f) && (col < valid_num[n]);
    int p = rowg * TT + col;
    if (i == n) {
      ws[S_OFF + i * PP + p] = m ? sig : -INFINITY;           // for hard-neg mining
      out[1 + i * PP + p] = m ? sig : NEG_SENTINEL;           // positive_map output
    }
    unsigned long long key = 0ull;
    if (m) key = ((unsigned long long)__float_as_uint(sig) << 32)
                 | (unsigned long long)(0xFFFFFFFFu - (unsigned)p);
#pragma unroll
    for (int mk = 1; mk < 64; mk <<= 1) {
      unsigned lo = __shfl_xor((unsigned)key, mk, 64);
      unsigned hi = __shfl_xor((unsigned)(key >> 32), mk, 64);
      unsigned long long o = ((unsigned long long)hi << 32) | lo;
      if (o > key) key = o;
    }
    if (lane == 0) kred[w] = key;
  }
  __syncthreads();
  if (t == 0) {
    unsigned long long k = kred[0];
    if (kred[1] > k) k = kred[1];
    if (k) atomicMax(&scp[i * 8 + n], k);
  }
}

// hard-negative mining: one block per sentence (8 blocks x 256 thr)
__global__ __launch_bounds__(256) void mine_kernel(
    const float* __restrict__ iou_maps, const float* __restrict__ lam,
    float* __restrict__ ws)
{
  __shared__ float wred[4];
  int i = blockIdx.x;
  int t = threadIdx.x, lane = t & 63, w = t >> 6;
  const unsigned long long* scp = (const unsigned long long*)(ws + SCP_OFF);

  unsigned long long dk = scp[i * 9];                  // diag (i,i)
  float diag_sc = __uint_as_float((unsigned)(dk >> 32));
  int pidx = (int)(0xFFFFFFFFu - (unsigned)(dk & 0xFFFFFFFFu));
  float lamv = lam[0];
  const float* row = iou_maps + (size_t)pidx * PP;
  const float* si = ws + S_OFF + (size_t)i * PP;
  float hv = -INFINITY;
  for (int p = t; p < PP; p += 256) {
    float v = si[p];
    if (row[p] < lamv && isfinite(v)) hv = fmaxf(hv, v);
  }
#pragma unroll
  for (int m = 1; m < 64; m <<= 1) hv = fmaxf(hv, __shfl_xor(hv, m, 64));
  if (lane == 0) wred[w] = hv;
  __syncthreads();
  if (t == 0) {
    float h = fmaxf(fmaxf(wred[0], wred[1]), fmaxf(wred[2], wred[3]));
    ws[NL_OFF + i] = fmaxf(0.f, MARGINF + h - diag_sc);
  }
}

// final loss: 1 wave, sorting-network top-3 (unchanged math)
__global__ __launch_bounds__(64) void loss_kernel(
    float* __restrict__ ws, float* __restrict__ out)
{
  __shared__ float scsh[64];
  int lane = threadIdx.x;
  const unsigned long long* scp = (const unsigned long long*)(ws + SCP_OFF);
  scsh[lane] = __uint_as_float((unsigned)(scp[lane] >> 32));
  __syncthreads();

  float partial = 0.f;
  if (lane < 16) {
    int r = lane & 7;
    bool im = lane >= 8;
    float diag = scsh[r * 8 + r];
    float v[8];
#pragma unroll
    for (int j = 0; j < 8; ++j) {
      float scv = im ? scsh[j * 8 + r] : scsh[r * 8 + j];
      float h = fmaxf(0.f, MARGINF + scv - diag);
      v[j] = (j == r) ? 0.f : h;
    }
#define CE(a, b) { float mx = fmaxf(v[a], v[b]); float mn = fminf(v[a], v[b]); v[a] = mx; v[b] = mn; }
    CE(0,1) CE(2,3) CE(4,5) CE(6,7)
    CE(0,2) CE(1,3) CE(4,6) CE(5,7)
    CE(1,2) CE(5,6)
    CE(0,4) CE(1,5) CE(2,6) CE(3,7)
    CE(2,4) CE(3,5)
    CE(1,2) CE(3,4) CE(5,6)
#undef CE
    partial = v[0] + v[1] + v[2];
  } else if (lane >= 16 && lane < 24) {
    partial = ws[NL_OFF + lane - 16];
  }
#pragma unroll
  for (int m = 1; m < 64; m <<= 1) partial += __shfl_xor(partial, m, 64);
  if (lane == 0) out[0] = partial * 0.125f;
}

extern "C" void kernel_launch(void* const* d_in, const int* in_sizes, int n_in,
                              void* d_out, int out_size, void* d_ws, size_t ws_size,
                              hipStream_t stream)
{
  const float* v_map     = (const float*)d_in[0];
  const float* words     = (const float*)d_in[1];
  const float* w_masks   = (const float*)d_in[2];
  const float* v_mask    = (const float*)d_in[3];
  const int*   valid_num = (const int*)d_in[4];
  const float* iou_maps  = (const float*)d_in[5];
  const float* lam       = (const float*)d_in[6];
  const float* Wc0 = (const float*)d_in[7];
  const float* bc0 = (const float*)d_in[8];
  const float* Wc1 = (const float*)d_in[9];
  const float* bc1 = (const float*)d_in[10];
  const float* Wp0 = (const float*)d_in[11];
  const float* bp0 = (const float*)d_in[12];
  const float* Wp1 = (const float*)d_in[13];
  const float* bp1 = (const float*)d_in[14];
  const float* W2d = (const float*)d_in[15];
  const float* b2d = (const float*)d_in[16];
  float* ws  = (float*)d_ws;
  float* out = (float*)d_out;

  hipLaunchKernelGGL(gates_kernel, dim3(8), dim3(256), 0, stream,
                     words, w_masks, Wp0, bp0, Wp1, bp1, ws);
  hipLaunchKernelGGL(setup_kernel, dim3(1665), dim3(256), 0, stream,
                     v_map, v_mask, Wc0, Wc1, ws);
  hipLaunchKernelGGL(conv1_mfma, dim3(66, 8), dim3(256), 0, stream, bc0, ws);
  hipLaunchKernelGGL(conv2_mfma, dim3(32, 64), dim3(256), 0, stream,
                     bc1, W2d, b2d, v_mask, valid_num, ws, out);
  hipLaunchKernelGGL(mine_kernel, dim3(8), dim3(256), 0, stream, iou_maps, lam, ws);
  hipLaunchKernelGGL(loss_kernel, dim3(1), dim3(64), 0, stream, ws, out);
}

// Round 12
// 133.752 us; speedup vs baseline: 1.3242x; 1.0563x over previous
//
#include <hip/hip_runtime.h>
#include <hip/hip_bf16.h>
#include <math.h>

#define BB 8
#define CC 128
#define DD 64
#define TT 64
#define PP 4096
#define H1 66
#define LW 20
#define MARGINF 0.1f
#define NEG_SENTINEL -1.0e30f

// workspace layout (float offsets)
#define Y0_OFF   0            // y0w bf16 channel-last [8][66][66][128] = 2230272 f
#define VT_OFF   2230272      // vT bf16 [8][64][64][128] = 2097152 f
#define BP0_OFF  4327424      // Bpack(Wc0) 16x16 layout = 73728 f
#define NL_OFF   4401152      // per-sentence neg-loss [8] (old BP1 slot, unused gap)
#define W0_OFF   4479236      // weight0 [66][66] = 4356
#define W1_OFF   4483592      // weight1 [64][64] = 4096
#define G0_OFF   4487688      // [8][128]
#define G1_OFF   4488712      // [8][128]
#define S_OFF    4489736      // si [8][4096] = 32768 (diag maps only)
#define SCP_OFF  4522504      // packed scores u64 [64] = 128 f
#define BP1S_OFF 4522632      // 8x gate-scaled Bpack(Wc1*g0[i]) = 8*73728 f = 589824 f
// total ≈ 5112456 floats ≈ 20.5 MB

typedef __attribute__((ext_vector_type(8))) short bf16x8;
typedef __attribute__((ext_vector_type(4))) float f32x4;

// LDS (row,col) stride in shorts: 44 (=88B), conflict-light b128 access
#define ASTR 44

__device__ __forceinline__ unsigned f2bf(float f) {
  union { float f; unsigned u; } v; v.f = f;
  unsigned r = v.u + 0x7fffu + ((v.u >> 16) & 1u);   // RNE (setup only)
  return r >> 16;
}
__device__ __forceinline__ float bf2f(unsigned hw) {
  union { unsigned u; float f; } v; v.u = hw << 16;
  return v.f;
}
// native cast: compiler emits v_cvt_pk for pairs (m240)
__device__ __forceinline__ unsigned cvt_bf(float x) {
  __hip_bfloat16 h = __float2bfloat16(x);
  union { __hip_bfloat16 h; unsigned short u; } cv; cv.h = h;
  return (unsigned)cv.u;
}

// sign-select on 2 packed bf16: keep half iff sign(v) == wanted sign bit in W.
// relu(g*v)*Wc1 == select(v) * (Wc1*g), select(v) = g>0 ? max(v,0) : min(v,0)
__device__ __forceinline__ unsigned selbf(unsigned d, unsigned W) {
  unsigned diff = (d ^ W) & 0x80008000u;     // sign mismatch bits
  unsigned full = (diff >> 15) * 0xFFFFu;    // expand to half-word masks
  return d & ~full;                          // zero mismatched halves
}

// ---------------- setup + gates fused (B1S moved to conv1 launch, so setup
// no longer reads g0 and gates can ride along as blocks 1089..1096)
__global__ __launch_bounds__(256) void setup_kernel(
    const float* __restrict__ vmap, const float* __restrict__ v_mask,
    const float* __restrict__ Wc0,
    const float* __restrict__ words, const float* __restrict__ w_masks,
    const float* __restrict__ Wp0, const float* __restrict__ bp0,
    const float* __restrict__ Wp1, const float* __restrict__ bp1,
    float* __restrict__ ws)
{
  __shared__ float smem[64 * 129];
  int bid = blockIdx.x;
  int t = threadIdx.x;

  if (bid < 576) {
    // B0 pack (unscaled)
    unsigned short* dst = (unsigned short*)(ws + BP0_OFF);
    int idx = bid * 256 + t;
    int j    = idx & 7;
    int lane = (idx >> 3) & 63;
    int cog  = (idx >> 9) & 7;
    int cic  = (idx >> 12) & 3;
    int kk   = idx >> 14;
    int co = cog * 16 + (lane & 15);
    int ci = cic * 32 + (lane >> 4) * 8 + j;
    dst[idx] = (unsigned short)f2bf(Wc0[(co * CC + ci) * 9 + kk]);
  } else if (bid < 1088) {
    unsigned short* vT = (unsigned short*)(ws + VT_OFF);
    int b = bid - 576;                   // 576 % 8 == 0 -> XCD = b & 7
    int n = b & 7, y = b >> 3;           // XCD-aligned: vT[n] stays in XCD n's L2
    int x = t & 63, c4 = t >> 6;
    for (int rep = 0; rep < 32; ++rep) {
      int ci = rep * 4 + c4;
      smem[x * 129 + ci] = vmap[(((size_t)n * CC + ci) * DD + y) * TT + x];
    }
    __syncthreads();
    for (int rep = 0; rep < 16; ++rep) {
      int v = t + rep * 256;
      int xx = v >> 6, cip = v & 63;
      float a = smem[xx * 129 + cip * 2];
      float b2 = smem[xx * 129 + cip * 2 + 1];
      unsigned pk = f2bf(a) | (f2bf(b2) << 16);
      *(unsigned*)&vT[(((size_t)(n * DD + y) * TT + xx)) * CC + cip * 2] = pk;
    }
  } else if (bid == 1088) {
    if (t < 128) ((unsigned*)(ws + SCP_OFF))[t] = 0u;   // zero packed scores
    float* w0 = ws + W0_OFF;
    float* w1 = ws + W1_OFF;
    for (int idx = t; idx < H1 * H1; idx += 256) {
      int y = idx / H1, x = idx % H1;
      float cnt = 0.f;
      for (int ky = 0; ky < 3; ++ky)
        for (int kx = 0; kx < 3; ++kx) {
          int iy = y + ky - 2, ix = x + kx - 2;
          if (iy >= 0 && iy < DD && ix >= 0 && ix < TT) cnt += v_mask[iy * TT + ix];
        }
      w0[idx] = (cnt > 0.f) ? 1.f / fmaxf(cnt, 1.f) : 0.f;
    }
    __syncthreads();
    for (int idx = t; idx < DD * TT; idx += 256) {
      int y = idx / TT, x = idx % TT;
      float cnt = 0.f;
      for (int ky = 0; ky < 3; ++ky)
        for (int kx = 0; kx < 3; ++kx)
          cnt += (w0[(y + ky) * H1 + (x + kx)] > 0.f) ? 1.f : 0.f;
      w1[idx] = (cnt > 0.f) ? 1.f / fmaxf(cnt, 1.f) : 0.f;
    }
  } else {
    // gates: pooled words -> g0,g1 (consumed by NEXT launch's B1S blocks)
    int i = bid - 1089;
    if (t < CC) {
      float wsum = 0.f, acc = 0.f;
      for (int l = 0; l < LW; ++l) {
        float wm = w_masks[i * LW + l];
        wsum += wm;
        acc += words[(i * LW + l) * CC + t] * wm;
      }
      smem[t] = acc / fmaxf(wsum, 1.f);
    }
    __syncthreads();
    {
      int c = t & 127;
      const float* Wp = (t < 128) ? Wp0 : Wp1;
      const float* bp = (t < 128) ? bp0 : bp1;
      float a = bp[c];
      for (int k = 0; k < CC; ++k) a += smem[k] * Wp[k * CC + c];
      float g = tanhf(a);
      float* gout = ws + ((t < 128) ? G0_OFF : G1_OFF);
      gout[i * CC + c] = g;
    }
  }
}

// conv1 (co-split: 1 row x 64 co per block, grid 1056 -> ~4 blocks/CU feed)
// + B1S pack riding as blocks 1056..1631 (fills idle CUs; only needs g0
// from the previous launch). XCD-aligned n = id&7 (R25, kept).
__global__ __launch_bounds__(256, 3) void conv1_mfma(
    const float* __restrict__ bc0, const float* __restrict__ Wc1,
    float* __restrict__ ws)
{
  __shared__ unsigned short Alds[3 * 68 * ASTR];   // 17952 B

  int t = threadIdx.x;
  int id = blockIdx.x;

  if (id >= 1056) {
    // B1S pack: read each Wc1 element ONCE, write 8 gate-scaled copies
    float* smem = (float*)Alds;                    // 4KB alias
    for (int v = t; v < 8 * CC; v += 256) smem[v] = ws[G0_OFF + v];
    __syncthreads();
    int idx = (id - 1056) * 256 + t;
    int j    = idx & 7;
    int lane = (idx >> 3) & 63;
    int cog  = (idx >> 9) & 7;
    int cic  = (idx >> 12) & 3;
    int kk   = idx >> 14;
    int co = cog * 16 + (lane & 15);
    int ci = cic * 32 + (lane >> 4) * 8 + j;
    float wv = Wc1[(co * CC + ci) * 9 + kk];
    unsigned short* dst = (unsigned short*)(ws + BP1S_OFF);
#pragma unroll
    for (int si = 0; si < 8; ++si)
      dst[si * 147456 + idx] = (unsigned short)f2bf(wv * smem[si * CC + ci]);
    return;
  }

  const unsigned short* vT = (const unsigned short*)(ws + VT_OFF);
  const unsigned short* Bp = (const unsigned short*)(ws + BP0_OFF);
  const float* w0arr = ws + W0_OFF;
  unsigned short* y0w = (unsigned short*)(ws + Y0_OFF);

  int n  = id & 7;                         // XCD-aligned
  int ch = (id >> 3) & 1;                  // co half 0..1
  int r0 = id >> 4;                        // output row 0..65
  int lane = t & 63, w = t >> 6;           // w = 16-co group within half
  int l15 = lane & 15, l4 = lane >> 4;
  int s = ch * 4 + w;                      // 16-co group 0..7
  int co0 = s * 16;

  f32x4 acc[5];
#pragma unroll
  for (int mf = 0; mf < 5; ++mf) acc[mf] = (f32x4){0.f, 0.f, 0.f, 0.f};

  for (int cic = 0; cic < 4; ++cic) {
    __syncthreads();
    for (int u = t; u < 816; u += 256) {
      int cig = u & 3, rest = u >> 2;
      int col = rest % 68, r = rest / 68;
      int iy = r0 - 2 + r, ix = col - 2;
      uint4 val = {0u, 0u, 0u, 0u};
      if (iy >= 0 && iy < DD && ix >= 0 && ix < TT)
        val = *(const uint4*)&vT[(((size_t)(n * DD + iy) * TT + ix)) * CC + cic * 32 + cig * 8];
      *(uint4*)&Alds[(r * 68 + col) * ASTR + cig * 8] = val;
    }
    __syncthreads();
    __builtin_amdgcn_s_setprio(1);
#pragma unroll
    for (int kk = 0; kk < 9; ++kk) {
      int ky = kk / 3, kx = kk % 3;
      bf16x8 af[5], bfr;
#pragma unroll
      for (int mf = 0; mf < 5; ++mf) {
        int c = mf * 16 + l15;
        int cc = c > 65 ? 65 : c;
        af[mf] = *(const bf16x8*)&Alds[(ky * 68 + cc + kx) * ASTR + l4 * 8];
      }
      bfr = *(const bf16x8*)&Bp[(((kk * 4 + cic) * 8 + s) * 64 + lane) * 8];
#pragma unroll
      for (int mf = 0; mf < 5; ++mf)
        acc[mf] = __builtin_amdgcn_mfma_f32_16x16x32_bf16(af[mf], bfr, acc[mf], 0, 0, 0);
    }
    __builtin_amdgcn_s_setprio(0);
  }

  int y = r0;
  {
    int co = co0 + l15;
    float bcv = bc0[co];
#pragma unroll
    for (int mf = 0; mf < 5; ++mf)
#pragma unroll
      for (int rg = 0; rg < 4; ++rg) {
        int c = mf * 16 + l4 * 4 + rg;
        if (c < H1) {
          float v = (acc[mf][rg] + bcv) * w0arr[y * H1 + c];
          y0w[((size_t)(n * H1 + y) * H1 + c) * CC + co] = (unsigned short)cvt_bf(v);
        }
      }
  }
}

// conv2: byte-identical to R26 (measured best, 81.4us): 2-row tiles,
// launch_bounds(256,3), selbf staging, global-B MFMA cluster.
__global__ __launch_bounds__(256, 3) void conv2_mfma(
    const float* __restrict__ bc1, const float* __restrict__ W2d,
    const float* __restrict__ b2d, const float* __restrict__ v_mask,
    const int* __restrict__ valid_num, float* __restrict__ ws,
    float* __restrict__ out)
{
  const unsigned short* y0w = (const unsigned short*)(ws + Y0_OFF);
  const float* w1m = ws + W1_OFF;
  const float* g0 = ws + G0_OFF;
  const float* g1 = ws + G1_OFF;
  unsigned long long* scp = (unsigned long long*)(ws + SCP_OFF);

  __shared__ unsigned short Alds[4 * 66 * ASTR];   // 23232 B
  __shared__ unsigned msk[16][4];                  // sign masks per (cic,cig)
  __shared__ float redl[2][2][64];
  __shared__ unsigned long long kred[2];

  int t = threadIdx.x;
  int r0 = blockIdx.x;                        // output rows r0*2, r0*2+1 (r0 in 0..31)
  int i = blockIdx.y & 7, n = blockIdx.y >> 3;   // n-major: L2 locality on y0w[n]
  int lane = t & 63, w = t >> 6;
  int wr = w >> 1, wc = w & 1;                // wr = row, wc = co half
  int l15 = lane & 15, l4 = lane >> 4;

  const unsigned short* Bp = (const unsigned short*)(ws + BP1S_OFF) + (size_t)i * 147456;

  if (t < 16) {                               // t = cic*4+cig -> channels t*8..t*8+7
    int ch = t * 8;
    msk[t][0] = (g0[i * CC + ch + 0] > 0.f ? 0u : 0x8000u) | (g0[i * CC + ch + 1] > 0.f ? 0u : 0x80000000u);
    msk[t][1] = (g0[i * CC + ch + 2] > 0.f ? 0u : 0x8000u) | (g0[i * CC + ch + 3] > 0.f ? 0u : 0x80000000u);
    msk[t][2] = (g0[i * CC + ch + 4] > 0.f ? 0u : 0x8000u) | (g0[i * CC + ch + 5] > 0.f ? 0u : 0x80000000u);
    msk[t][3] = (g0[i * CC + ch + 6] > 0.f ? 0u : 0x8000u) | (g0[i * CC + ch + 7] > 0.f ? 0u : 0x80000000u);
  }

  f32x4 acc[4][4];
#pragma unroll
  for (int mf = 0; mf < 4; ++mf)
#pragma unroll
    for (int nf = 0; nf < 4; ++nf) acc[mf][nf] = (f32x4){0.f, 0.f, 0.f, 0.f};

  for (int cic = 0; cic < 4; ++cic) {
    __syncthreads();
    // stage 4 rows x 66 cols x 32ci: 1056 uint4s; select applied via sign bits
    {
      uint4 mv = *(const uint4*)&msk[(cic << 2) | (t & 3)][0];
      for (int u = t; u < 1056; u += 256) {
        int cig = u & 3, cr = u >> 2;
        int col = cr % 66, row = cr / 66;       // row 0..3
        const unsigned short* src = y0w
            + ((size_t)((n * H1 + r0 * 2 + row) * H1 + col)) * CC + cic * 32 + cig * 8;
        uint4 raw = *(const uint4*)src;
        uint4 pk;
        pk.x = selbf(raw.x, mv.x);
        pk.y = selbf(raw.y, mv.y);
        pk.z = selbf(raw.z, mv.z);
        pk.w = selbf(raw.w, mv.w);
        *(uint4*)&Alds[(row * 66 + col) * ASTR + cig * 8] = pk;
      }
    }
    __syncthreads();
    __builtin_amdgcn_s_setprio(1);
#pragma unroll
    for (int kk = 0; kk < 9; ++kk) {
      int ky = kk / 3, kx = kk % 3;
      bf16x8 af[4], bfr[4];
#pragma unroll
      for (int mf = 0; mf < 4; ++mf) {
        int row = wr + ky;                          // 0..3
        int col = mf * 16 + l15 + kx;               // 0..65
        af[mf] = *(const bf16x8*)&Alds[(row * 66 + col) * ASTR + l4 * 8];
      }
#pragma unroll
      for (int nf = 0; nf < 4; ++nf)
        bfr[nf] = *(const bf16x8*)&Bp[(((kk * 4 + cic) * 8 + wc * 4 + nf) * 64 + lane) * 8];
#pragma unroll
      for (int mf = 0; mf < 4; ++mf)
#pragma unroll
        for (int nf = 0; nf < 4; ++nf)
          acc[mf][nf] = __builtin_amdgcn_mfma_f32_16x16x32_bf16(af[mf], bfr[nf], acc[mf][nf], 0, 0, 0);
    }
    __builtin_amdgcn_s_setprio(0);
  }

  // epilogue: relu((acc+bc1)*g1)*W2d, reduce over co; weight1 factored out (w1>=0)
  float part[4][4];
#pragma unroll
  for (int mf = 0; mf < 4; ++mf)
#pragma unroll
    for (int rg = 0; rg < 4; ++rg) part[mf][rg] = 0.f;
#pragma unroll
  for (int nf = 0; nf < 4; ++nf) {
    int co = wc * 64 + nf * 16 + l15;
    float bcv = bc1[co];
    float gv = g1[i * CC + co];
    float wv = W2d[co];
#pragma unroll
    for (int mf = 0; mf < 4; ++mf)
#pragma unroll
      for (int rg = 0; rg < 4; ++rg) {
        float z = (acc[mf][nf][rg] + bcv) * gv;
        part[mf][rg] += fmaxf(z, 0.f) * wv;
      }
  }
#pragma unroll
  for (int mask = 1; mask < 16; mask <<= 1)
#pragma unroll
    for (int mf = 0; mf < 4; ++mf)
#pragma unroll
      for (int rg = 0; rg < 4; ++rg)
        part[mf][rg] += __shfl_xor(part[mf][rg], mask, 64);
  if (l15 == 0) {
#pragma unroll
    for (int mf = 0; mf < 4; ++mf)
#pragma unroll
      for (int rg = 0; rg < 4; ++rg)
        redl[wc][wr][mf * 16 + l4 * 4 + rg] = part[mf][rg];
  }
  __syncthreads();
  if (t < 128) {
    int row = t >> 6, col = t & 63;             // row 0..1
    int rowg = r0 * 2 + row;
    float v = redl[0][row][col] + redl[1][row][col];
    float logit = w1m[rowg * TT + col] * v + b2d[0];
    float sig = 1.f / (1.f + expf(-logit));
    bool m = (v_mask[rowg * TT + col] > 0.f) && (col < valid_num[n]);
    int p = rowg * TT + col;
    if (i == n) {
      ws[S_OFF + i * PP + p] = m ? sig : -INFINITY;           // for hard-neg mining
      out[1 + i * PP + p] = m ? sig : NEG_SENTINEL;           // positive_map output
    }
    unsigned long long key = 0ull;
    if (m) key = ((unsigned long long)__float_as_uint(sig) << 32)
                 | (unsigned long long)(0xFFFFFFFFu - (unsigned)p);
#pragma unroll
    for (int mk = 1; mk < 64; mk <<= 1) {
      unsigned lo = __shfl_xor((unsigned)key, mk, 64);
      unsigned hi = __shfl_xor((unsigned)(key >> 32), mk, 64);
      unsigned long long o = ((unsigned long long)hi << 32) | lo;
      if (o > key) key = o;
    }
    if (lane == 0) kred[w] = key;
  }
  __syncthreads();
  if (t == 0) {
    unsigned long long k = kred[0];
    if (kred[1] > k) k = kred[1];
    if (k) atomicMax(&scp[i * 8 + n], k);
  }
}

// hard-negative mining: one block per sentence (8 blocks x 256 thr)
__global__ __launch_bounds__(256) void mine_kernel(
    const float* __restrict__ iou_maps, const float* __restrict__ lam,
    float* __restrict__ ws)
{
  __shared__ float wred[4];
  int i = blockIdx.x;
  int t = threadIdx.x, lane = t & 63, w = t >> 6;
  const unsigned long long* scp = (const unsigned long long*)(ws + SCP_OFF);

  unsigned long long dk = scp[i * 9];                  // diag (i,i)
  float diag_sc = __uint_as_float((unsigned)(dk >> 32));
  int pidx = (int)(0xFFFFFFFFu - (unsigned)(dk & 0xFFFFFFFFu));
  float lamv = lam[0];
  const float* row = iou_maps + (size_t)pidx * PP;
  const float* si = ws + S_OFF + (size_t)i * PP;
  float hv = -INFINITY;
  for (int p = t; p < PP; p += 256) {
    float v = si[p];
    if (row[p] < lamv && isfinite(v)) hv = fmaxf(hv, v);
  }
#pragma unroll
  for (int m = 1; m < 64; m <<= 1) hv = fmaxf(hv, __shfl_xor(hv, m, 64));
  if (lane == 0) wred[w] = hv;
  __syncthreads();
  if (t == 0) {
    float h = fmaxf(fmaxf(wred[0], wred[1]), fmaxf(wred[2], wred[3]));
    ws[NL_OFF + i] = fmaxf(0.f, MARGINF + h - diag_sc);
  }
}

// final loss: 1 wave, sorting-network top-3 (unchanged math)
__global__ __launch_bounds__(64) void loss_kernel(
    float* __restrict__ ws, float* __restrict__ out)
{
  __shared__ float scsh[64];
  int lane = threadIdx.x;
  const unsigned long long* scp = (const unsigned long long*)(ws + SCP_OFF);
  scsh[lane] = __uint_as_float((unsigned)(scp[lane] >> 32));
  __syncthreads();

  float partial = 0.f;
  if (lane < 16) {
    int r = lane & 7;
    bool im = lane >= 8;
    float diag = scsh[r * 8 + r];
    float v[8];
#pragma unroll
    for (int j = 0; j < 8; ++j) {
      float scv = im ? scsh[j * 8 + r] : scsh[r * 8 + j];
      float h = fmaxf(0.f, MARGINF + scv - diag);
      v[j] = (j == r) ? 0.f : h;
    }
#define CE(a, b) { float mx = fmaxf(v[a], v[b]); float mn = fminf(v[a], v[b]); v[a] = mx; v[b] = mn; }
    CE(0,1) CE(2,3) CE(4,5) CE(6,7)
    CE(0,2) CE(1,3) CE(4,6) CE(5,7)
    CE(1,2) CE(5,6)
    CE(0,4) CE(1,5) CE(2,6) CE(3,7)
    CE(2,4) CE(3,5)
    CE(1,2) CE(3,4) CE(5,6)
#undef CE
    partial = v[0] + v[1] + v[2];
  } else if (lane >= 16 && lane < 24) {
    partial = ws[NL_OFF + lane - 16];
  }
#pragma unroll
  for (int m = 1; m < 64; m <<= 1) partial += __shfl_xor(partial, m, 64);
  if (lane == 0) out[0] = partial * 0.125f;
}

extern "C" void kernel_launch(void* const* d_in, const int* in_sizes, int n_in,
                              void* d_out, int out_size, void* d_ws, size_t ws_size,
                              hipStream_t stream)
{
  const float* v_map     = (const float*)d_in[0];
  const float* words     = (const float*)d_in[1];
  const float* w_masks   = (const float*)d_in[2];
  const float* v_mask    = (const float*)d_in[3];
  const int*   valid_num = (const int*)d_in[4];
  const float* iou_maps  = (const float*)d_in[5];
  const float* lam       = (const float*)d_in[6];
  const float* Wc0 = (const float*)d_in[7];
  const float* bc0 = (const float*)d_in[8];
  const float* Wc1 = (const float*)d_in[9];
  const float* bc1 = (const float*)d_in[10];
  const float* Wp0 = (const float*)d_in[11];
  const float* bp0 = (const float*)d_in[12];
  const float* Wp1 = (const float*)d_in[13];
  const float* bp1 = (const float*)d_in[14];
  const float* W2d = (const float*)d_in[15];
  const float* b2d = (const float*)d_in[16];
  float* ws  = (float*)d_ws;
  float* out = (float*)d_out;

  hipLaunchKernelGGL(setup_kernel, dim3(1097), dim3(256), 0, stream,
                     v_map, v_mask, Wc0, words, w_masks, Wp0, bp0, Wp1, bp1, ws);
  hipLaunchKernelGGL(conv1_mfma, dim3(1632), dim3(256), 0, stream, bc0, Wc1, ws);
  hipLaunchKernelGGL(conv2_mfma, dim3(32, 64), dim3(256), 0, stream,
                     bc1, W2d, b2d, v_mask, valid_num, ws, out);
  hipLaunchKernelGGL(mine_kernel, dim3(8), dim3(256), 0, stream, iou_maps, lam, ws);
  hipLaunchKernelGGL(loss_kernel, dim3(1), dim3(64), 0, stream, ws, out);
}